// Round 6
// baseline (329.780 us; speedup 1.0000x reference)
//
#include <hip/hip_runtime.h>
#include <stdint.h>

// MHA fused: qkv-proj + out-proj (m201-class 4-phase dbuf GEMM, register-held
// operands -> 2-tile stage lead, one counted vmcnt per K-tile) + causal flash attn.
// B=2, S=2048, H=2048, heads=16, D=128.

using bf16x8 = __attribute__((ext_vector_type(8))) __bf16;
using f32x4  = __attribute__((ext_vector_type(4))) float;

#define S_LEN 2048
#define HID   2048
#define NHEAD 16
#define DHEAD 128
#define KDIM  2048
#define QSCALE_L2E (0.08838834764831845f * 1.4426950408889634f)

__device__ __forceinline__ unsigned short f2bf(float f) {
  union { float f; unsigned int u; } c; c.f = f;
  unsigned int u = c.u;
  return (unsigned short)((u + 0x7FFFu + ((u >> 16) & 1u)) >> 16);  // RNE
}

__device__ __forceinline__ unsigned int pkbf(float a, float b) {
  union { __bf16 h[2]; unsigned int u; } x;
  x.h[0] = (__bf16)a; x.h[1] = (__bf16)b;
  return x.u;
}

__device__ __forceinline__ void gload_lds16(const void* g, void* l) {
  __builtin_amdgcn_global_load_lds(
      (const __attribute__((address_space(1))) unsigned int*)g,
      (__attribute__((address_space(3))) unsigned int*)l, 16, 0, 0);
}

__device__ __forceinline__ f32x4 mfma16(bf16x8 a, bf16x8 b, f32x4 c) {
  return __builtin_amdgcn_mfma_f32_16x16x32_bf16(a, b, c, 0, 0, 0);
}

__device__ __forceinline__ float hmax4(f32x4 v) {
  return fmaxf(fmaxf(v[0], v[1]), fmaxf(v[2], v[3]));
}

__global__ void cvt_bf16(const float* __restrict__ in, unsigned short* __restrict__ out, int n) {
  const int n4 = n >> 2;
  const int stride = gridDim.x * blockDim.x;
  for (int i = blockIdx.x * blockDim.x + threadIdx.x; i < n4; i += stride) {
    float4 v = reinterpret_cast<const float4*>(in)[i];
    ushort4 o;
    o.x = f2bf(v.x); o.y = f2bf(v.y); o.z = f2bf(v.z); o.w = f2bf(v.w);
    reinterpret_cast<ushort4*>(out)[i] = o;
  }
}

#define BAR   asm volatile("s_barrier" ::: "memory")
#define LGKM0 do { asm volatile("s_waitcnt lgkmcnt(0)" ::: "memory"); \
                   __builtin_amdgcn_sched_barrier(0); } while (0)
#define VM(n) asm volatile("s_waitcnt vmcnt(" #n ")" ::: "memory")
#define PRIO1 __builtin_amdgcn_s_setprio(1)
#define PRIO0 __builtin_amdgcn_s_setprio(0)

// ============================================================================
// QKV GEMM: C(4096 x 6144) = A * Wqkv^T + b -> scatter to Q/K/Vt (bf16).
// 256x256 tile, BK=64, 512 thr = 8 waves (2m x 4n), wave 128x64, acc 8x4.
// LDS 128 KB: lsA[2][256 rows][128B], lsB same; swizzle byte^=((row&7)<<4)
// (measured 0 bank conflicts, rounds 2/4).
// Schedule per K-tile t (4 phases, 16 MFMA each):
//  ph1: ds{a_lo 8, bB(t) 4}  stage B(t+2)[4 ld]  | mfma a_lo x bA(t)
//  ph2: ds{a_hi 8}                               | mfma a_hi x bA(t)
//  ph3: ds{bA(t+1) 4 [next slot]} stage A0(t+2)  | mfma a_lo x bB(t)
//  ph4:                     stage A1(t+2)        | mfma a_hi x bB(t); vmcnt(4)
// Ledger (induction): after ph4(t)-wait flying = A(t+2)[4 loads]; the wait
// drains A(t+1) (staged ph3/4(t-1), ~5 phases old) and B(t+2) (staged ph1(t),
// 3 phases old) -> no steady-state stall. Slot safety: B(t+2) DMA lands in
// slot t&1 whose reads (bA ph3(t-1), bB ph1(t)... bB(t) read ph1(t) BEFORE
// stage issue same phase? No: bB(t) ds_read is issued before the stage in
// program order and all waves sit between the same barriers; DMA data cannot
// land before its own issue, and bB(t) reads complete under the ph1 LGKM0
// which precedes any wave's ph2. A(t+2) lands in slot t&1 after a-reads
// completed at ph2-end barrier. Prologue: B0,A0,B1,A1 staged; vmcnt(4).
// ============================================================================
__global__ __launch_bounds__(512, 2) void gemm_qkv(
    const unsigned short* __restrict__ A, const unsigned short* __restrict__ Bw,
    const float* __restrict__ bias,
    unsigned short* __restrict__ q_out, unsigned short* __restrict__ k_out,
    unsigned short* __restrict__ vt_out)
{
  __shared__ char lsA[2][32768];
  __shared__ char lsB[2][32768];
  const int tid = threadIdx.x, l = tid & 63, w = tid >> 6;
  const int wr = w >> 2, wc = w & 3;
  const int row16 = l & 15, kg = l >> 4;

  // XCD-chunked swizzle: 384 blocks, 48/XCD (16 bm x 3 bn -> 3MB B-panels in L2)
  const int bid = blockIdx.x;
  const int swz = (bid & 7) * 48 + (bid >> 3);
  const int bm = (swz & 15) * 256, bn = (swz >> 4) * 256;
  const char* Ag = (const char*)A + (size_t)bm * (KDIM * 2);
  const char* Bg = (const char*)Bw + (size_t)bn * (KDIM * 2);

  f32x4 acc[8][4] = {};

#define STAGE_B(cc) do { _Pragma("unroll")                                     \
    for (int p = 0; p < 4; ++p) {                                              \
      const int o = p * 8192 + tid * 16;                                       \
      const int r = o >> 7;                                                    \
      const int cb = (o & 127) ^ ((r & 7) << 4);                               \
      gload_lds16(Bg + (size_t)r * (KDIM * 2) + (cc) * 128 + cb,               \
                  lsB[(cc) & 1] + o);                                          \
    } } while (0)

#define STAGE_A(cc, g) do { _Pragma("unroll")                                  \
    for (int p = 0; p < 2; ++p) {                                              \
      const int o = p * 8192 + tid * 16;                                       \
      const int rl = o >> 7;                                                   \
      const int r = (g) * 128 + rl;                                            \
      const int cb = (o & 127) ^ ((r & 7) << 4);                               \
      gload_lds16(Ag + (size_t)r * (KDIM * 2) + (cc) * 128 + cb,               \
                  lsA[(cc) & 1] + (g) * 16384 + o);                            \
    } } while (0)

#define RD_A(dst, i0, Ac) do { _Pragma("unroll")                               \
    for (int i = 0; i < 4; ++i) {                                              \
      const int m = wr * 128 + ((i0) + i) * 16 + row16;                        \
      _Pragma("unroll")                                                        \
      for (int h = 0; h < 2; ++h)                                              \
        dst[i][h] = *(const bf16x8*)((Ac) + m * 128 +                          \
                    ((h * 64 + kg * 16) ^ ((m & 7) << 4)));                    \
    } } while (0)

#define RD_B(dst, j0, Bc) do { _Pragma("unroll")                               \
    for (int j = 0; j < 2; ++j) {                                              \
      const int n = wc * 64 + ((j0) + j) * 16 + row16;                         \
      _Pragma("unroll")                                                        \
      for (int h = 0; h < 2; ++h)                                              \
        dst[j][h] = *(const bf16x8*)((Bc) + n * 128 +                          \
                    ((h * 64 + kg * 16) ^ ((n & 7) << 4)));                    \
    } } while (0)

#define MM(af, bf, i0, j0) do { _Pragma("unroll")                              \
    for (int i = 0; i < 4; ++i) { _Pragma("unroll")                            \
      for (int j = 0; j < 2; ++j) { _Pragma("unroll")                          \
        for (int h = 0; h < 2; ++h)                                            \
          acc[(i0) + i][(j0) + j] =                                            \
            mfma16(af[i][h], bf[j][h], acc[(i0) + i][(j0) + j]);               \
    } } } while (0)

  // prologue: B(0), A(0), B(1), A(1); vmcnt(4) -> B0,A0,B1 landed, A1 flying
  STAGE_B(0); STAGE_A(0, 0); STAGE_A(0, 1);
  STAGE_B(1); STAGE_A(1, 0); STAGE_A(1, 1);
  VM(4);
  BAR;

  bf16x8 alo[4][2], ahi[4][2], bA[2][2], bB[2][2];
  RD_B(bA, 0, lsB[0]);   // bA(0)
  LGKM0;

  #pragma unroll 1
  for (int t = 0; t < 32; ++t) {
    const char* Ac = lsA[t & 1];
    const char* Bc = lsB[t & 1];
    const char* Bn = lsB[(t + 1) & 1];

    // ---- ph1: a_lo + bB(t); stage B(t+2); mfma a_lo x bA(t)
    RD_A(alo, 0, Ac);
    RD_B(bB, 2, Bc);
    if (t < 30) STAGE_B(t + 2);
    BAR; LGKM0;
    PRIO1; MM(alo, bA, 0, 0); PRIO0;
    BAR;

    // ---- ph2: a_hi; mfma a_hi x bA(t)
    RD_A(ahi, 4, Ac);
    BAR; LGKM0;
    PRIO1; MM(ahi, bA, 4, 0); PRIO0;
    BAR;

    // ---- ph3: bA(t+1) from next slot; stage A0(t+2); mfma a_lo x bB(t)
    if (t < 31) RD_B(bA, 0, Bn);
    if (t < 30) STAGE_A(t + 2, 0);
    BAR; LGKM0;
    PRIO1; MM(alo, bB, 0, 2); PRIO0;
    BAR;

    // ---- ph4: stage A1(t+2); mfma a_hi x bB(t); counted wait
    if (t < 30) STAGE_A(t + 2, 1);
    BAR;
    PRIO1; MM(ahi, bB, 4, 2); PRIO0;
    if (t < 30)       { VM(4); }
    else if (t == 30) { VM(0); }
    BAR;
  }
#undef STAGE_B
#undef STAGE_A
#undef RD_A
#undef RD_B
#undef MM

  // scatter epilogue: C/D layout col = lane&15, row = (lane>>4)*4 + reg
  #pragma unroll
  for (int j = 0; j < 4; ++j) {
    const int col = bn + wc * 64 + j * 16 + row16;
    const float bvj = bias[col];
    const int sec = col >> 11;           // 0=Q 1=K 2=V
    const int within = col & 2047;
    const int head = within >> 7, d = within & 127;
    #pragma unroll
    for (int i = 0; i < 8; ++i) {
      const int row = bm + wr * 128 + i * 16 + kg * 4;
      #pragma unroll
      for (int r = 0; r < 4; ++r) {
        const int rr = row + r;
        const int b = rr >> 11, s = rr & 2047;
        const int bh2 = b * NHEAD + head;
        const float v = acc[i][j][r] + bvj;
        if (sec == 0)
          q_out[((size_t)bh2 * S_LEN + s) * DHEAD + d] = f2bf(v * QSCALE_L2E);
        else if (sec == 1)
          k_out[((size_t)bh2 * S_LEN + s) * DHEAD + d] = f2bf(v);
        else
          vt_out[((size_t)bh2 * DHEAD + d) * S_LEN + s] = f2bf(v);
      }
    }
  }
}

// ============================================================================
// Out-projection: C(4096 x 2048) = A * Wout^T + b, fp32. Tile 128x256,
// grid 256 exact. 8 waves (2m x 4n), wave 64x64, acc 4x4. LDS 96 KB dbuf.
// 2 phases/tile: p0: ds{a 8, b01(t) 4} stage B(t+1) | mfma a x b01
//                p1: ds{b23(t) 4}      stage A(t+2) | mfma a x b23; vmcnt(2)
// Wait drains A(t+1) (2 phases old) + B(t+1) (1.5 phases, L2-warm weights).
// ============================================================================
__global__ __launch_bounds__(512, 2) void gemm_out(
    const unsigned short* __restrict__ A, const unsigned short* __restrict__ Bw,
    const float* __restrict__ bias, float* __restrict__ c_out)
{
  __shared__ char lsA[2][16384];
  __shared__ char lsB[2][32768];
  const int tid = threadIdx.x, l = tid & 63, w = tid >> 6;
  const int wr = w >> 2, wc = w & 3;
  const int row16 = l & 15, kg = l >> 4;

  const int bid = blockIdx.x;
  const int swz = (bid & 7) * 32 + (bid >> 3);
  const int bm = (swz & 31) * 128, bn = (swz >> 5) * 256;
  const char* Ag = (const char*)A + (size_t)bm * (KDIM * 2);
  const char* Bg = (const char*)Bw + (size_t)bn * (KDIM * 2);

  f32x4 acc[4][4] = {};

#define STAGE_B(cc) do { _Pragma("unroll")                                     \
    for (int p = 0; p < 4; ++p) {                                              \
      const int o = p * 8192 + tid * 16;                                       \
      const int r = o >> 7;                                                    \
      const int cb = (o & 127) ^ ((r & 7) << 4);                               \
      gload_lds16(Bg + (size_t)r * (KDIM * 2) + (cc) * 128 + cb,               \
                  lsB[(cc) & 1] + o);                                          \
    } } while (0)

#define STAGE_A(cc) do { _Pragma("unroll")                                     \
    for (int p = 0; p < 2; ++p) {                                              \
      const int o = p * 8192 + tid * 16;                                       \
      const int r = o >> 7;                                                    \
      const int cb = (o & 127) ^ ((r & 7) << 4);                               \
      gload_lds16(Ag + (size_t)r * (KDIM * 2) + (cc) * 128 + cb,               \
                  lsA[(cc) & 1] + o);                                          \
    } } while (0)

#define RD_A(dst, Ac) do { _Pragma("unroll")                                   \
    for (int i = 0; i < 4; ++i) {                                              \
      const int m = wr * 64 + i * 16 + row16;                                  \
      _Pragma("unroll")                                                        \
      for (int h = 0; h < 2; ++h)                                              \
        dst[i][h] = *(const bf16x8*)((Ac) + m * 128 +                          \
                    ((h * 64 + kg * 16) ^ ((m & 7) << 4)));                    \
    } } while (0)

#define RD_B(dst, j0, Bc) do { _Pragma("unroll")                               \
    for (int j = 0; j < 2; ++j) {                                              \
      const int n = wc * 64 + ((j0) + j) * 16 + row16;                         \
      _Pragma("unroll")                                                        \
      for (int h = 0; h < 2; ++h)                                              \
        dst[j][h] = *(const bf16x8*)((Bc) + n * 128 +                          \
                    ((h * 64 + kg * 16) ^ ((n & 7) << 4)));                    \
    } } while (0)

#define MM(af, bf, j0) do { _Pragma("unroll")                                  \
    for (int i = 0; i < 4; ++i) { _Pragma("unroll")                            \
      for (int j = 0; j < 2; ++j) { _Pragma("unroll")                          \
        for (int h = 0; h < 2; ++h)                                            \
          acc[i][(j0) + j] = mfma16(af[i][h], bf[j][h], acc[i][(j0) + j]);     \
    } } } while (0)

  // prologue: B(0), A(0), A(1); vmcnt(2) -> B0,A0 landed, A1 flying
  STAGE_B(0); STAGE_A(0); STAGE_A(1);
  VM(2);
  BAR;

  bf16x8 af[4][2], b01[2][2], b23[2][2];

  #pragma unroll 1
  for (int t = 0; t < 32; ++t) {
    const char* Ac = lsA[t & 1];
    const char* Bc = lsB[t & 1];

    // ---- p0: a + b01; stage B(t+1); mfma a x b01
    RD_A(af, Ac);
    RD_B(b01, 0, Bc);
    if (t < 31) STAGE_B(t + 1);
    BAR; LGKM0;
    PRIO1; MM(af, b01, 0); PRIO0;
    BAR;

    // ---- p1: b23; stage A(t+2); mfma a x b23; counted wait
    RD_B(b23, 2, Bc);
    if (t < 30) STAGE_A(t + 2);
    BAR; LGKM0;
    PRIO1; MM(af, b23, 2); PRIO0;
    if (t < 30)       { VM(2); }
    else if (t == 30) { VM(0); }
    BAR;
  }
#undef STAGE_B
#undef STAGE_A
#undef RD_A
#undef RD_B
#undef MM

  #pragma unroll
  for (int i = 0; i < 4; ++i) {
    const int row = bm + wr * 64 + i * 16 + kg * 4;
    #pragma unroll
    for (int j = 0; j < 4; ++j) {
      const int col = bn + wc * 64 + j * 16 + row16;
      const float bvj = bias[col];
      #pragma unroll
      for (int r = 0; r < 4; ++r)
        c_out[(size_t)(row + r) * HID + col] = acc[i][j][r] + bvj;
    }
  }
}

// Causal flash attention: swapped QK^T, 32 q-rows/wave, 2-phase dbuf pipeline.
__global__ __launch_bounds__(256, 2) void attn_fwd(
    const unsigned short* __restrict__ Q, const unsigned short* __restrict__ Kk,
    const unsigned short* __restrict__ Vt, unsigned short* __restrict__ O)
{
  __shared__ char lsK[2][64 * 256];
  __shared__ char lsV[2][128 * 128];
  __shared__ char lsP[4][32 * 128];
  const int tid = threadIdx.x, l = tid & 63, w = tid >> 6;
  const int row16 = l & 15, kg = l >> 4;
  const int qb = (blockIdx.y < 16) ? (15 - (int)blockIdx.x) : (int)blockIdx.x;
  const int bh = blockIdx.y;
  const int bidx = bh >> 4, head = bh & 15;

  const char* Qh = (const char*)(Q  + (size_t)bh * S_LEN * DHEAD);
  const char* Kh = (const char*)(Kk + (size_t)bh * S_LEN * DHEAD);
  const char* Vh = (const char*)(Vt + (size_t)bh * DHEAD * S_LEN);

  const int q0w = qb * 128 + w * 32;

  bf16x8 qf[2][4];
  #pragma unroll
  for (int qs = 0; qs < 2; ++qs)
    #pragma unroll
    for (int t = 0; t < 4; ++t)
      qf[qs][t] = *(const bf16x8*)(Qh + ((size_t)(q0w + qs * 16 + row16) * DHEAD + t * 32 + kg * 8) * 2);

  float m[2]  = {-1e30f, -1e30f};
  float ls[2] = {0.f, 0.f};
  f32x4 oacc[2][8] = {};

  const int last = 2 * qb + 1;

#define STAGE(buf, kt_) do {                                                     \
    _Pragma("unroll")                                                            \
    for (int c = 0; c < 4; ++c) {                                                \
      const int o = c * 4096 + tid * 16;                                         \
      const int rk = o >> 8, cbk = (o & 255) ^ ((rk & 7) << 4);                  \
      gload_lds16(Kh + (size_t)((kt_) * 64 + rk) * 256 + cbk,                    \
                  lsK[buf] + c * 4096 + (w << 10));                              \
      const int dv = o >> 7, cbv = (o & 127) ^ ((dv & 7) << 4);                  \
      gload_lds16(Vh + (size_t)dv * 4096 + (size_t)(kt_) * 128 + cbv,            \
                  lsV[buf] + c * 4096 + (w << 10));                              \
    } } while (0)

  STAGE(0, 0);
  __syncthreads();

  int cur = 0;
  for (int kt = 0; ; ++kt) {
    if (kt < last) STAGE(cur ^ 1, kt + 1);

    if (kt * 64 <= q0w + 31) {
      const char* Kc = lsK[cur];
      const char* Vc = lsV[cur];
      char* Pl = lsP[w];

      f32x4 sc[4][2] = {};
      #pragma unroll
      for (int j = 0; j < 4; ++j) {
        const int krow = j * 16 + row16;
        const int sw = (krow & 7) << 4;
        bf16x8 kf[4];
        #pragma unroll
        for (int t = 0; t < 4; ++t)
          kf[t] = *(const bf16x8*)(Kc + krow * 256 + ((t * 64 + kg * 16) ^ sw));
        #pragma unroll
        for (int t = 0; t < 4; ++t) {
          sc[j][0] = mfma16(kf[t], qf[0][t], sc[j][0]);
          sc[j][1] = mfma16(kf[t], qf[1][t], sc[j][1]);
        }
      }

      if (kt >= 2 * qb) {
        #pragma unroll
        for (int j = 0; j < 4; ++j) {
          const int kvb = kt * 64 + j * 16 + kg * 4;
          #pragma unroll
          for (int qs = 0; qs < 2; ++qs) {
            const int qq = q0w + qs * 16 + row16;
            #pragma unroll
            for (int r = 0; r < 4; ++r)
              if (kvb + r > qq) sc[j][qs][r] = -1e30f;
          }
        }
      }

      float pm[2], al[2] = {1.f, 1.f};
      #pragma unroll
      for (int qs = 0; qs < 2; ++qs) {
        float mx = fmaxf(fmaxf(hmax4(sc[0][qs]), hmax4(sc[1][qs])),
                         fmaxf(hmax4(sc[2][qs]), hmax4(sc[3][qs])));
        mx = fmaxf(mx, __shfl_xor(mx, 16, 64));
        mx = fmaxf(mx, __shfl_xor(mx, 32, 64));
        pm[qs] = mx;
      }
      const bool need = (pm[0] > m[0] + 8.f) || (pm[1] > m[1] + 8.f);
      if (__any(need)) {
        const float n0 = fmaxf(m[0], pm[0]), n1 = fmaxf(m[1], pm[1]);
        al[0] = exp2f(m[0] - n0); al[1] = exp2f(m[1] - n1);
        m[0] = n0; m[1] = n1;
        float aq[2][4];
        #pragma unroll
        for (int qs2 = 0; qs2 < 2; ++qs2)
          #pragma unroll
          for (int r = 0; r < 4; ++r)
            aq[qs2][r] = __shfl(al[qs2], kg * 4 + r, 64);
        #pragma unroll
        for (int qs2 = 0; qs2 < 2; ++qs2)
          #pragma unroll
          for (int dt = 0; dt < 8; ++dt)
            #pragma unroll
            for (int r = 0; r < 4; ++r)
              oacc[qs2][dt][r] *= aq[qs2][r];
      }

      #pragma unroll
      for (int qs = 0; qs < 2; ++qs) {
        const int q = qs * 16 + row16;
        const int psw = (q & 7) << 4;
        float ps = 0.f;
        #pragma unroll
        for (int j = 0; j < 4; ++j) {
          const float p0 = exp2f(sc[j][qs][0] - m[qs]);
          const float p1 = exp2f(sc[j][qs][1] - m[qs]);
          const float p2 = exp2f(sc[j][qs][2] - m[qs]);
          const float p3 = exp2f(sc[j][qs][3] - m[qs]);
          ps += (p0 + p1) + (p2 + p3);
          uint2 pw; pw.x = pkbf(p0, p1); pw.y = pkbf(p2, p3);
          *(uint2*)(Pl + q * 128 + ((j * 32 + kg * 8) ^ psw)) = pw;
        }
        ps += __shfl_xor(ps, 16, 64);
        ps += __shfl_xor(ps, 32, 64);
        ls[qs] = ls[qs] * al[qs] + ps;
      }

      bf16x8 pa[2][2];
      #pragma unroll
      for (int qs2 = 0; qs2 < 2; ++qs2) {
        const int q = qs2 * 16 + row16;
        #pragma unroll
        for (int ks = 0; ks < 2; ++ks)
          pa[qs2][ks] = *(const bf16x8*)(Pl + q * 128 + ((ks * 64 + kg * 16) ^ ((q & 7) << 4)));
      }
      #pragma unroll
      for (int dt = 0; dt < 8; ++dt) {
        const int drow = dt * 16 + row16;
        const int vsw = (drow & 7) << 4;
        bf16x8 v0 = *(const bf16x8*)(Vc + drow * 128 + ((kg * 16) ^ vsw));
        bf16x8 v1 = *(const bf16x8*)(Vc + drow * 128 + ((64 + kg * 16) ^ vsw));
        oacc[0][dt] = mfma16(pa[0][0], v0, oacc[0][dt]);
        oacc[0][dt] = mfma16(pa[0][1], v1, oacc[0][dt]);
        oacc[1][dt] = mfma16(pa[1][0], v0, oacc[1][dt]);
        oacc[1][dt] = mfma16(pa[1][1], v1, oacc[1][dt]);
      }
    }

    __syncthreads();
    if (kt == last) break;
    cur ^= 1;
  }
#undef STAGE

  #pragma unroll
  for (int qs2 = 0; qs2 < 2; ++qs2) {
    #pragma unroll
    for (int r = 0; r < 4; ++r) {
      const float lr = __shfl(ls[qs2], kg * 4 + r, 64);
      const float inv = 1.0f / lr;
      const int q = q0w + qs2 * 16 + kg * 4 + r;
      const size_t orow = (size_t)(bidx * S_LEN + q) * HID + (size_t)head * DHEAD;
      #pragma unroll
      for (int dt = 0; dt < 8; ++dt)
        O[orow + dt * 16 + row16] = f2bf(oacc[qs2][dt][r] * inv);
    }
  }
}

extern "C" void kernel_launch(void* const* d_in, const int* in_sizes, int n_in,
                              void* d_out, int out_size, void* d_ws, size_t ws_size,
                              hipStream_t stream) {
  const float* x    = (const float*)d_in[0];
  const float* Wqkv = (const float*)d_in[1];
  const float* bqkv = (const float*)d_in[2];
  const float* Wout = (const float*)d_in[3];
  const float* bout = (const float*)d_in[4];
  float* out = (float*)d_out;

  if (ws_size < 100663296) return;  // insufficient scratch -> clean validation fail
  char* ws = (char*)d_ws;
  unsigned short* Qb    = (unsigned short*)(ws);
  unsigned short* Kb    = (unsigned short*)(ws + 16777216);
  unsigned short* Vtb   = (unsigned short*)(ws + 2 * 16777216);
  unsigned short* xb    = (unsigned short*)(ws + 3 * 16777216);
  unsigned short* Ob    = xb;  // alias: xb dead after QKV GEMM, Ob written after
  unsigned short* Wqkvb = (unsigned short*)(ws + 4 * 16777216);
  unsigned short* Woutb = (unsigned short*)(ws + 4 * 16777216 + 25165824);

  cvt_bf16<<<2048, 256, 0, stream>>>(x,    xb,    4096 * 2048);
  cvt_bf16<<<2048, 256, 0, stream>>>(Wqkv, Wqkvb, 6144 * 2048);
  cvt_bf16<<<1024, 256, 0, stream>>>(Wout, Woutb, 2048 * 2048);

  // QKV: 16 x 24 tiles of 256^2 -> 384 blocks
  gemm_qkv<<<384, 512, 0, stream>>>(xb, Wqkvb, bqkv, Qb, Kb, Vtb);
  attn_fwd<<<dim3(16, 32), 256, 0, stream>>>(Qb, Kb, Vtb, Ob);
  // OUT: 32 x 8 tiles of 128x256 -> 256 blocks (one full residency round)
  gemm_out<<<256, 512, 0, stream>>>(Ob, Woutb, bout, out);
}

// Round 7
// 313.953 us; speedup vs baseline: 1.0504x; 1.0504x over previous
//
#include <hip/hip_runtime.h>
#include <stdint.h>

// MHA fused: qkv-proj (faithful m201 8-phase GEMM) -> causal flash attn -> out-proj.
// B=2, S=2048, H=2048, heads=16, D=128.

using bf16x8 = __attribute__((ext_vector_type(8))) __bf16;
using f32x4  = __attribute__((ext_vector_type(4))) float;

#define S_LEN 2048
#define HID   2048
#define NHEAD 16
#define DHEAD 128
#define KDIM  2048
#define QSCALE_L2E (0.08838834764831845f * 1.4426950408889634f)

__device__ __forceinline__ unsigned short f2bf(float f) {
  union { float f; unsigned int u; } c; c.f = f;
  unsigned int u = c.u;
  return (unsigned short)((u + 0x7FFFu + ((u >> 16) & 1u)) >> 16);  // RNE
}

__device__ __forceinline__ unsigned int pkbf(float a, float b) {
  union { __bf16 h[2]; unsigned int u; } x;
  x.h[0] = (__bf16)a; x.h[1] = (__bf16)b;
  return x.u;
}

__device__ __forceinline__ void gload_lds16(const void* g, void* l) {
  __builtin_amdgcn_global_load_lds(
      (const __attribute__((address_space(1))) unsigned int*)g,
      (__attribute__((address_space(3))) unsigned int*)l, 16, 0, 0);
}

__device__ __forceinline__ f32x4 mfma16(bf16x8 a, bf16x8 b, f32x4 c) {
  return __builtin_amdgcn_mfma_f32_16x16x32_bf16(a, b, c, 0, 0, 0);
}

__device__ __forceinline__ float hmax4(f32x4 v) {
  return fmaxf(fmaxf(v[0], v[1]), fmaxf(v[2], v[3]));
}

__global__ void cvt_bf16(const float* __restrict__ in, unsigned short* __restrict__ out, int n) {
  const int n4 = n >> 2;
  const int stride = gridDim.x * blockDim.x;
  for (int i = blockIdx.x * blockDim.x + threadIdx.x; i < n4; i += stride) {
    float4 v = reinterpret_cast<const float4*>(in)[i];
    ushort4 o;
    o.x = f2bf(v.x); o.y = f2bf(v.y); o.z = f2bf(v.z); o.w = f2bf(v.w);
    reinterpret_cast<ushort4*>(out)[i] = o;
  }
}

#define BAR   asm volatile("s_barrier" ::: "memory")
#define LGKM0 do { asm volatile("s_waitcnt lgkmcnt(0)" ::: "memory"); \
                   __builtin_amdgcn_sched_barrier(0); } while (0)
#define VM(n) asm volatile("s_waitcnt vmcnt(" #n ")" ::: "memory")
#define PRIO1 __builtin_amdgcn_s_setprio(1)
#define PRIO0 __builtin_amdgcn_s_setprio(0)

// ============================================================================
// QKV GEMM — m201 8-phase template, ledger-faithful.
// C(4096 x 6144) = A * Wqkv^T + b -> scatter to Q/K/Vt (bf16).
// 256x256 tile, BK=64, 512 thr = 8 waves (2m x 4n), wave 128x64, acc 8x4.
// LDS 128 KB: per buffer, A and B each stored as 2 HALF-TILES of 16 KB.
// Halves defined by phase read-sets (union over waves):
//   A half h: rows with ((m>>6)&1)==h   (ph1 reads h=0, ph2 reads h=1)
//   B half h: rows with ((n>>5)&1)==h   (ph1 reads h=0, ph3 reads h=1)
// LDS addr: A: half*16384 + ((m>>7)&1)*8192 + (m&63)*128 + swz-col
//           B: half*16384 + (n>>6)*4096   + (n&31)*128 + swz-col
// Col swizzle byte^=((row&7)<<4) — measured 0 bank conflicts (r2/r4/r6);
// inverse applied to per-lane GLOBAL source, LDS dest linear (m173).
//
// Iteration i computes K-tiles t0=2i (buf0) and t0+1 (buf1), 8 phases:
//  ph1: rd a_lo,b_lo(buf0); stage B_hi(t0+1)   | mfma (m-lo,n-lo)
//  ph2: rd a_hi(buf0);      stage A_lo(t0+2)   | mfma (m-hi,n-lo)
//  ph3: rd b_hi(buf0);      stage B_lo(t0+2)   | mfma (m-lo,n-hi)
//  ph4:                     stage A_hi(t0+2)   | mfma (m-hi,n-hi); VM(6)
//  ph5-8: same on buf1, staging B_hi(t0+2), A_lo/B_lo/A_hi(t0+3); VM(6) @ph8
// Ledger (induction, 2 loads/stage): entering iter i: 6 outstanding
// (A_lo,B_lo,A_hi of t0+1). ph1-4 add 8 -> 14; VM(6) drains the 8 oldest =
// tile t0+1's 4 halves (reads ph5,6,7 OK). ph5-8 add 8 -> 14; VM(6) drains
// tile t0+2's 4 halves (reads ph1,2,3 of iter i+1 OK). Every stage lands
// 6-7 phases after issue (~1.5 K-tiles lead >> HBM latency). Slot safety:
// each slot re-staged exactly one phase after its ds_read (LGKM0+barrier
// separate them). Prologue: 7 halves, VM(6). Tail (tiles 30,31): stage only
// B_hi(31) @ph1; VM(2) @ph4, VM(0) @ph6.
// ============================================================================
__global__ __launch_bounds__(512, 2) void gemm_qkv(
    const unsigned short* __restrict__ A, const unsigned short* __restrict__ Bw,
    const float* __restrict__ bias,
    unsigned short* __restrict__ q_out, unsigned short* __restrict__ k_out,
    unsigned short* __restrict__ vt_out)
{
  __shared__ char lsA[2][32768];
  __shared__ char lsB[2][32768];
  const int tid = threadIdx.x, l = tid & 63, w = tid >> 6;
  const int wr = w >> 2, wc = w & 3;
  const int row16 = l & 15, kg = l >> 4;

  // XCD-chunked swizzle: 384 blocks, 48/XCD
  const int bid = blockIdx.x;
  const int swz = (bid & 7) * 48 + (bid >> 3);
  const int bm = (swz & 15) * 256, bn = (swz >> 4) * 256;
  const char* Ag = (const char*)A + (size_t)bm * (KDIM * 2);
  const char* Bg = (const char*)Bw + (size_t)bn * (KDIM * 2);

  f32x4 acc[8][4] = {};

  // stage half h of A-tile cc into buf cc&1 (2 gload_lds / thread)
#define STAGE_A(cc, h) do { _Pragma("unroll")                                  \
    for (int p = 0; p < 2; ++p) {                                              \
      const int o = p * 8192 + tid * 16;                                       \
      const int lr = o >> 7;                                                   \
      const int m = ((lr >> 6) << 7) + (h) * 64 + (lr & 63);                   \
      const int cb = (o & 127) ^ ((m & 7) << 4);                               \
      gload_lds16(Ag + (size_t)m * (KDIM * 2) + (size_t)(cc) * 128 + cb,       \
                  lsA[(cc) & 1] + (h) * 16384 + p * 8192 + (w << 10));         \
    } } while (0)

#define STAGE_B(cc, h) do { _Pragma("unroll")                                  \
    for (int p = 0; p < 2; ++p) {                                              \
      const int o = p * 8192 + tid * 16;                                       \
      const int lr = o >> 7;                                                   \
      const int n = ((lr >> 5) << 6) + (h) * 32 + (lr & 31);                   \
      const int cb = (o & 127) ^ ((n & 7) << 4);                               \
      gload_lds16(Bg + (size_t)n * (KDIM * 2) + (size_t)(cc) * 128 + cb,       \
                  lsB[(cc) & 1] + (h) * 16384 + p * 8192 + (w << 10));         \
    } } while (0)

#define RD_A(dst, i0, buf) do { _Pragma("unroll")                              \
    for (int i = 0; i < 4; ++i) {                                              \
      const int m = wr * 128 + ((i0) + i) * 16 + row16;                        \
      const char* base = lsA[buf] + (((m >> 6) & 1) * 16384)                   \
                       + (((m >> 7) & 1) * 8192) + ((m & 63) * 128);           \
      _Pragma("unroll")                                                        \
      for (int h = 0; h < 2; ++h)                                              \
        dst[i][h] = *(const bf16x8*)(base +                                    \
                    ((h * 64 + kg * 16) ^ ((m & 7) << 4)));                    \
    } } while (0)

#define RD_B(dst, j0, buf) do { _Pragma("unroll")                              \
    for (int j = 0; j < 2; ++j) {                                              \
      const int n = wc * 64 + ((j0) + j) * 16 + row16;                         \
      const char* base = lsB[buf] + (((n >> 5) & 1) * 16384)                   \
                       + ((n >> 6) * 4096) + ((n & 31) * 128);                 \
      _Pragma("unroll")                                                        \
      for (int h = 0; h < 2; ++h)                                              \
        dst[j][h] = *(const bf16x8*)(base +                                    \
                    ((h * 64 + kg * 16) ^ ((n & 7) << 4)));                    \
    } } while (0)

#define MM(af, bf, i0, j0) do { _Pragma("unroll")                              \
    for (int i = 0; i < 4; ++i) { _Pragma("unroll")                            \
      for (int j = 0; j < 2; ++j) { _Pragma("unroll")                          \
        for (int h = 0; h < 2; ++h)                                            \
          acc[(i0) + i][(j0) + j] =                                            \
            mfma16(af[i][h], bf[j][h], acc[(i0) + i][(j0) + j]);               \
    } } } while (0)

  // prologue: tile0 (4 halves) + tile1 (3 halves) = 14 loads; VM(6) -> tile0 landed
  STAGE_A(0, 0); STAGE_B(0, 0); STAGE_A(0, 1); STAGE_B(0, 1);
  STAGE_A(1, 0); STAGE_B(1, 0); STAGE_A(1, 1);
  VM(6);
  BAR;

  bf16x8 alo[4][2], ahi[4][2], blo[2][2], bhi[2][2];

  #pragma unroll 1
  for (int i = 0; i < 15; ++i) {
    const int t0 = 2 * i;
    // ---- ph1
    RD_A(alo, 0, 0); RD_B(blo, 0, 0);
    STAGE_B(t0 + 1, 1);
    BAR; LGKM0;
    PRIO1; MM(alo, blo, 0, 0); PRIO0;
    BAR;
    // ---- ph2
    RD_A(ahi, 4, 0);
    STAGE_A(t0 + 2, 0);
    BAR; LGKM0;
    PRIO1; MM(ahi, blo, 4, 0); PRIO0;
    BAR;
    // ---- ph3
    RD_B(bhi, 2, 0);
    STAGE_B(t0 + 2, 0);
    BAR; LGKM0;
    PRIO1; MM(alo, bhi, 0, 2); PRIO0;
    BAR;
    // ---- ph4
    STAGE_A(t0 + 2, 1);
    BAR;
    PRIO1; MM(ahi, bhi, 4, 2); PRIO0;
    VM(6);
    BAR;
    // ---- ph5
    RD_A(alo, 0, 1); RD_B(blo, 0, 1);
    STAGE_B(t0 + 2, 1);
    BAR; LGKM0;
    PRIO1; MM(alo, blo, 0, 0); PRIO0;
    BAR;
    // ---- ph6
    RD_A(ahi, 4, 1);
    STAGE_A(t0 + 3, 0);
    BAR; LGKM0;
    PRIO1; MM(ahi, blo, 4, 0); PRIO0;
    BAR;
    // ---- ph7
    RD_B(bhi, 2, 1);
    STAGE_B(t0 + 3, 0);
    BAR; LGKM0;
    PRIO1; MM(alo, bhi, 0, 2); PRIO0;
    BAR;
    // ---- ph8
    STAGE_A(t0 + 3, 1);
    BAR;
    PRIO1; MM(ahi, bhi, 4, 2); PRIO0;
    VM(6);
    BAR;
  }
  { // ---- tail: tiles 30 (buf0), 31 (buf1); stages off except B_hi(31)
    // ph1
    RD_A(alo, 0, 0); RD_B(blo, 0, 0);
    STAGE_B(31, 1);
    BAR; LGKM0;
    PRIO1; MM(alo, blo, 0, 0); PRIO0;
    BAR;
    // ph2
    RD_A(ahi, 4, 0);
    BAR; LGKM0;
    PRIO1; MM(ahi, blo, 4, 0); PRIO0;
    BAR;
    // ph3
    RD_B(bhi, 2, 0);
    BAR; LGKM0;
    PRIO1; MM(alo, bhi, 0, 2); PRIO0;
    BAR;
    // ph4
    PRIO1; MM(ahi, bhi, 4, 2); PRIO0;
    VM(2);   // tile-31 A_lo,B_lo,A_hi landed
    BAR;
    // ph5
    RD_A(alo, 0, 1); RD_B(blo, 0, 1);
    BAR; LGKM0;
    PRIO1; MM(alo, blo, 0, 0); PRIO0;
    BAR;
    // ph6
    RD_A(ahi, 4, 1);
    BAR; LGKM0;
    PRIO1; MM(ahi, blo, 4, 0); PRIO0;
    VM(0);   // B_hi(31) landed
    BAR;
    // ph7
    RD_B(bhi, 2, 1);
    LGKM0;
    PRIO1; MM(alo, bhi, 0, 2); PRIO0;
    // ph8
    PRIO1; MM(ahi, bhi, 4, 2); PRIO0;
  }
#undef STAGE_A
#undef STAGE_B
#undef RD_A
#undef RD_B
#undef MM

  // scatter epilogue: C/D layout col = lane&15, row = (lane>>4)*4 + reg
  #pragma unroll
  for (int j = 0; j < 4; ++j) {
    const int col = bn + wc * 64 + j * 16 + row16;
    const float bvj = bias[col];
    const int sec = col >> 11;           // 0=Q 1=K 2=V
    const int within = col & 2047;
    const int head = within >> 7, d = within & 127;
    #pragma unroll
    for (int i = 0; i < 8; ++i) {
      const int row = bm + wr * 128 + i * 16 + kg * 4;
      #pragma unroll
      for (int r = 0; r < 4; ++r) {
        const int rr = row + r;
        const int b = rr >> 11, s = rr & 2047;
        const int bh2 = b * NHEAD + head;
        const float v = acc[i][j][r] + bvj;
        if (sec == 0)
          q_out[((size_t)bh2 * S_LEN + s) * DHEAD + d] = f2bf(v * QSCALE_L2E);
        else if (sec == 1)
          k_out[((size_t)bh2 * S_LEN + s) * DHEAD + d] = f2bf(v);
        else
          vt_out[((size_t)bh2 * DHEAD + d) * S_LEN + s] = f2bf(v);
      }
    }
  }
}

// Out-projection: round-2 proven 128x128-tile GEMM, fp32 epilogue.
__global__ __launch_bounds__(256) void gemm_out(
    const unsigned short* __restrict__ A, const unsigned short* __restrict__ Bw,
    const float* __restrict__ bias, float* __restrict__ c_out)
{
  constexpr int K = KDIM, N = HID;
  __shared__ char lsA[128 * 128];
  __shared__ char lsB[128 * 128];
  const int tid = threadIdx.x;
  const int l = tid & 63, w = tid >> 6;
  const int wr = w >> 1, wc = w & 1;
  const int bm = blockIdx.x * 128, bn = blockIdx.y * 128;
  const int row16 = l & 15, kg = l >> 4;

  f32x4 acc[4][4] = {};

  for (int k0 = 0; k0 < K; k0 += 64) {
    #pragma unroll
    for (int c = 0; c < 4; ++c) {
      const int o = c * 4096 + tid * 16;
      const int r = o >> 7;
      const int cb = (o & 127) ^ ((r & 7) << 4);
      gload_lds16((const char*)A + ((size_t)(bm + r) * K + k0) * 2 + cb,
                  lsA + c * 4096 + (w << 10));
      gload_lds16((const char*)Bw + ((size_t)(bn + r) * K + k0) * 2 + cb,
                  lsB + c * 4096 + (w << 10));
    }
    __syncthreads();

    #pragma unroll
    for (int h = 0; h < 2; ++h) {
      bf16x8 af[4], bfr[4];
      #pragma unroll
      for (int i = 0; i < 4; ++i) {
        const int ra = wr * 64 + i * 16 + row16;
        af[i]  = *(const bf16x8*)(lsA + ra * 128 + ((h * 64 + kg * 16) ^ ((ra & 7) << 4)));
        const int rb = wc * 64 + i * 16 + row16;
        bfr[i] = *(const bf16x8*)(lsB + rb * 128 + ((h * 64 + kg * 16) ^ ((rb & 7) << 4)));
      }
      #pragma unroll
      for (int i = 0; i < 4; ++i)
        #pragma unroll
        for (int j = 0; j < 4; ++j)
          acc[i][j] = mfma16(af[i], bfr[j], acc[i][j]);
    }
    __syncthreads();
  }

  #pragma unroll
  for (int i = 0; i < 4; ++i) {
    const int row = bm + wr * 64 + i * 16 + kg * 4;
    #pragma unroll
    for (int j = 0; j < 4; ++j) {
      const int col = bn + wc * 64 + j * 16 + row16;
      const float bvj = bias[col];
      #pragma unroll
      for (int r = 0; r < 4; ++r)
        c_out[(size_t)(row + r) * N + col] = acc[i][j][r] + bvj;
    }
  }
}

// Causal flash attention: swapped QK^T, 32 q-rows/wave, 2-phase dbuf pipeline.
__global__ __launch_bounds__(256, 2) void attn_fwd(
    const unsigned short* __restrict__ Q, const unsigned short* __restrict__ Kk,
    const unsigned short* __restrict__ Vt, unsigned short* __restrict__ O)
{
  __shared__ char lsK[2][64 * 256];
  __shared__ char lsV[2][128 * 128];
  __shared__ char lsP[4][32 * 128];
  const int tid = threadIdx.x, l = tid & 63, w = tid >> 6;
  const int row16 = l & 15, kg = l >> 4;
  const int qb = (blockIdx.y < 16) ? (15 - (int)blockIdx.x) : (int)blockIdx.x;
  const int bh = blockIdx.y;
  const int bidx = bh >> 4, head = bh & 15;

  const char* Qh = (const char*)(Q  + (size_t)bh * S_LEN * DHEAD);
  const char* Kh = (const char*)(Kk + (size_t)bh * S_LEN * DHEAD);
  const char* Vh = (const char*)(Vt + (size_t)bh * DHEAD * S_LEN);

  const int q0w = qb * 128 + w * 32;

  bf16x8 qf[2][4];
  #pragma unroll
  for (int qs = 0; qs < 2; ++qs)
    #pragma unroll
    for (int t = 0; t < 4; ++t)
      qf[qs][t] = *(const bf16x8*)(Qh + ((size_t)(q0w + qs * 16 + row16) * DHEAD + t * 32 + kg * 8) * 2);

  float m[2]  = {-1e30f, -1e30f};
  float ls[2] = {0.f, 0.f};
  f32x4 oacc[2][8] = {};

  const int last = 2 * qb + 1;

#define STAGE(buf, kt_) do {                                                     \
    _Pragma("unroll")                                                            \
    for (int c = 0; c < 4; ++c) {                                                \
      const int o = c * 4096 + tid * 16;                                         \
      const int rk = o >> 8, cbk = (o & 255) ^ ((rk & 7) << 4);                  \
      gload_lds16(Kh + (size_t)((kt_) * 64 + rk) * 256 + cbk,                    \
                  lsK[buf] + c * 4096 + (w << 10));                              \
      const int dv = o >> 7, cbv = (o & 127) ^ ((dv & 7) << 4);                  \
      gload_lds16(Vh + (size_t)dv * 4096 + (size_t)(kt_) * 128 + cbv,            \
                  lsV[buf] + c * 4096 + (w << 10));                              \
    } } while (0)

  STAGE(0, 0);
  __syncthreads();

  int cur = 0;
  for (int kt = 0; ; ++kt) {
    if (kt < last) STAGE(cur ^ 1, kt + 1);

    if (kt * 64 <= q0w + 31) {
      const char* Kc = lsK[cur];
      const char* Vc = lsV[cur];
      char* Pl = lsP[w];

      f32x4 sc[4][2] = {};
      #pragma unroll
      for (int j = 0; j < 4; ++j) {
        const int krow = j * 16 + row16;
        const int sw = (krow & 7) << 4;
        bf16x8 kf[4];
        #pragma unroll
        for (int t = 0; t < 4; ++t)
          kf[t] = *(const bf16x8*)(Kc + krow * 256 + ((t * 64 + kg * 16) ^ sw));
        #pragma unroll
        for (int t = 0; t < 4; ++t) {
          sc[j][0] = mfma16(kf[t], qf[0][t], sc[j][0]);
          sc[j][1] = mfma16(kf[t], qf[1][t], sc[j][1]);
        }
      }

      if (kt >= 2 * qb) {
        #pragma unroll
        for (int j = 0; j < 4; ++j) {
          const int kvb = kt * 64 + j * 16 + kg * 4;
          #pragma unroll
          for (int qs = 0; qs < 2; ++qs) {
            const int qq = q0w + qs * 16 + row16;
            #pragma unroll
            for (int r = 0; r < 4; ++r)
              if (kvb + r > qq) sc[j][qs][r] = -1e30f;
          }
        }
      }

      float pm[2], al[2] = {1.f, 1.f};
      #pragma unroll
      for (int qs = 0; qs < 2; ++qs) {
        float mx = fmaxf(fmaxf(hmax4(sc[0][qs]), hmax4(sc[1][qs])),
                         fmaxf(hmax4(sc[2][qs]), hmax4(sc[3][qs])));
        mx = fmaxf(mx, __shfl_xor(mx, 16, 64));
        mx = fmaxf(mx, __shfl_xor(mx, 32, 64));
        pm[qs] = mx;
      }
      const bool need = (pm[0] > m[0] + 8.f) || (pm[1] > m[1] + 8.f);
      if (__any(need)) {
        const float n0 = fmaxf(m[0], pm[0]), n1 = fmaxf(m[1], pm[1]);
        al[0] = exp2f(m[0] - n0); al[1] = exp2f(m[1] - n1);
        m[0] = n0; m[1] = n1;
        float aq[2][4];
        #pragma unroll
        for (int qs2 = 0; qs2 < 2; ++qs2)
          #pragma unroll
          for (int r = 0; r < 4; ++r)
            aq[qs2][r] = __shfl(al[qs2], kg * 4 + r, 64);
        #pragma unroll
        for (int qs2 = 0; qs2 < 2; ++qs2)
          #pragma unroll
          for (int dt = 0; dt < 8; ++dt)
            #pragma unroll
            for (int r = 0; r < 4; ++r)
              oacc[qs2][dt][r] *= aq[qs2][r];
      }

      #pragma unroll
      for (int qs = 0; qs < 2; ++qs) {
        const int q = qs * 16 + row16;
        const int psw = (q & 7) << 4;
        float ps = 0.f;
        #pragma unroll
        for (int j = 0; j < 4; ++j) {
          const float p0 = exp2f(sc[j][qs][0] - m[qs]);
          const float p1 = exp2f(sc[j][qs][1] - m[qs]);
          const float p2 = exp2f(sc[j][qs][2] - m[qs]);
          const float p3 = exp2f(sc[j][qs][3] - m[qs]);
          ps += (p0 + p1) + (p2 + p3);
          uint2 pw; pw.x = pkbf(p0, p1); pw.y = pkbf(p2, p3);
          *(uint2*)(Pl + q * 128 + ((j * 32 + kg * 8) ^ psw)) = pw;
        }
        ps += __shfl_xor(ps, 16, 64);
        ps += __shfl_xor(ps, 32, 64);
        ls[qs] = ls[qs] * al[qs] + ps;
      }

      bf16x8 pa[2][2];
      #pragma unroll
      for (int qs2 = 0; qs2 < 2; ++qs2) {
        const int q = qs2 * 16 + row16;
        #pragma unroll
        for (int ks = 0; ks < 2; ++ks)
          pa[qs2][ks] = *(const bf16x8*)(Pl + q * 128 + ((ks * 64 + kg * 16) ^ ((q & 7) << 4)));
      }
      #pragma unroll
      for (int dt = 0; dt < 8; ++dt) {
        const int drow = dt * 16 + row16;
        const int vsw = (drow & 7) << 4;
        bf16x8 v0 = *(const bf16x8*)(Vc + drow * 128 + ((kg * 16) ^ vsw));
        bf16x8 v1 = *(const bf16x8*)(Vc + drow * 128 + ((64 + kg * 16) ^ vsw));
        oacc[0][dt] = mfma16(pa[0][0], v0, oacc[0][dt]);
        oacc[0][dt] = mfma16(pa[0][1], v1, oacc[0][dt]);
        oacc[1][dt] = mfma16(pa[1][0], v0, oacc[1][dt]);
        oacc[1][dt] = mfma16(pa[1][1], v1, oacc[1][dt]);
      }
    }

    __syncthreads();
    if (kt == last) break;
    cur ^= 1;
  }
#undef STAGE

  #pragma unroll
  for (int qs2 = 0; qs2 < 2; ++qs2) {
    #pragma unroll
    for (int r = 0; r < 4; ++r) {
      const float lr = __shfl(ls[qs2], kg * 4 + r, 64);
      const float inv = 1.0f / lr;
      const int q = q0w + qs2 * 16 + kg * 4 + r;
      const size_t orow = (size_t)(bidx * S_LEN + q) * HID + (size_t)head * DHEAD;
      #pragma unroll
      for (int dt = 0; dt < 8; ++dt)
        O[orow + dt * 16 + row16] = f2bf(oacc[qs2][dt][r] * inv);
    }
  }
}

extern "C" void kernel_launch(void* const* d_in, const int* in_sizes, int n_in,
                              void* d_out, int out_size, void* d_ws, size_t ws_size,
                              hipStream_t stream) {
  const float* x    = (const float*)d_in[0];
  const float* Wqkv = (const float*)d_in[1];
  const float* bqkv = (const float*)d_in[2];
  const float* Wout = (const float*)d_in[3];
  const float* bout = (const float*)d_in[4];
  float* out = (float*)d_out;

  if (ws_size < 100663296) return;  // insufficient scratch -> clean validation fail
  char* ws = (char*)d_ws;
  unsigned short* Qb    = (unsigned short*)(ws);
  unsigned short* Kb    = (unsigned short*)(ws + 16777216);
  unsigned short* Vtb   = (unsigned short*)(ws + 2 * 16777216);
  unsigned short* xb    = (unsigned short*)(ws + 3 * 16777216);
  unsigned short* Ob    = xb;  // alias: xb dead after QKV GEMM, Ob written after
  unsigned short* Wqkvb = (unsigned short*)(ws + 4 * 16777216);
  unsigned short* Woutb = (unsigned short*)(ws + 4 * 16777216 + 25165824);

  cvt_bf16<<<2048, 256, 0, stream>>>(x,    xb,    4096 * 2048);
  cvt_bf16<<<2048, 256, 0, stream>>>(Wqkv, Wqkvb, 6144 * 2048);
  cvt_bf16<<<1024, 256, 0, stream>>>(Wout, Woutb, 2048 * 2048);

  // QKV: 16 x 24 tiles of 256^2 -> 384 blocks
  gemm_qkv<<<384, 512, 0, stream>>>(xb, Wqkvb, bqkv, Qb, Kb, Vtb);
  attn_fwd<<<dim3(16, 32), 256, 0, stream>>>(Qb, Kb, Vtb, Ob);
  gemm_out<<<dim3(32, 16), 256, 0, stream>>>(Ob, Woutb, bout, out);
}

// Round 8
// 301.387 us; speedup vs baseline: 1.0942x; 1.0417x over previous
//
#include <hip/hip_runtime.h>
#include <stdint.h>

// MHA fused: qkv-proj (bf16 MFMA GEMM, m97-class high-occupancy structure)
// -> causal flash attn -> out-proj.  B=2, S=2048, H=2048, heads=16, D=128.
// Round-8: round-2 proven base + T1 XCD-chunked grid swizzle (GEMMs)
//          + T5 setprio on attn MFMA clusters.

using bf16x8 = __attribute__((ext_vector_type(8))) __bf16;
using f32x4  = __attribute__((ext_vector_type(4))) float;

#define S_LEN 2048
#define HID   2048
#define NHEAD 16
#define DHEAD 128
// 1/sqrt(128) * log2(e): attention softmax runs in exp2 domain
#define QSCALE_L2E (0.08838834764831845f * 1.4426950408889634f)

__device__ __forceinline__ unsigned short f2bf(float f) {
  union { float f; unsigned int u; } c; c.f = f;
  unsigned int u = c.u;
  return (unsigned short)((u + 0x7FFFu + ((u >> 16) & 1u)) >> 16);  // RNE
}

__device__ __forceinline__ unsigned int pkbf(float a, float b) {
  union { __bf16 h[2]; unsigned int u; } x;
  x.h[0] = (__bf16)a; x.h[1] = (__bf16)b;
  return x.u;
}

__device__ __forceinline__ void gload_lds16(const void* g, void* l) {
  __builtin_amdgcn_global_load_lds(
      (const __attribute__((address_space(1))) unsigned int*)g,
      (__attribute__((address_space(3))) unsigned int*)l, 16, 0, 0);
}

__device__ __forceinline__ f32x4 mfma16(bf16x8 a, bf16x8 b, f32x4 c) {
  return __builtin_amdgcn_mfma_f32_16x16x32_bf16(a, b, c, 0, 0, 0);
}

__device__ __forceinline__ float hmax4(f32x4 v) {
  return fmaxf(fmaxf(v[0], v[1]), fmaxf(v[2], v[3]));
}

__global__ void cvt_bf16(const float* __restrict__ in, unsigned short* __restrict__ out, int n) {
  const int n4 = n >> 2;
  const int stride = gridDim.x * blockDim.x;
  for (int i = blockIdx.x * blockDim.x + threadIdx.x; i < n4; i += stride) {
    float4 v = reinterpret_cast<const float4*>(in)[i];
    ushort4 o;
    o.x = f2bf(v.x); o.y = f2bf(v.y); o.z = f2bf(v.z); o.w = f2bf(v.w);
    reinterpret_cast<ushort4*>(out)[i] = o;
  }
}

// C = A(M x K) * B(N x K)^T + bias.  128x128 tile, BK=64, 4 waves (2x2 of 64x64).
// EPI=0: QKV scatter epilogue (bf16), 32x48 tiles.  EPI=1: fp32 C, 32x16 tiles.
// 1D grid + bijective XCD-chunked swizzle (T1): m-fastest within each XCD's
// contiguous chunk -> B panels (0.5 MB x ~6) L2-resident per XCD.
template<int EPI>
__global__ __launch_bounds__(256) void gemm_bt(
    const unsigned short* __restrict__ A, const unsigned short* __restrict__ Bw,
    const float* __restrict__ bias, int K, int N,
    unsigned short* __restrict__ q_out, unsigned short* __restrict__ k_out,
    unsigned short* __restrict__ vt_out, float* __restrict__ c_out)
{
  constexpr int MT  = 32;
  constexpr int NT  = (EPI == 0) ? 48 : 16;
  constexpr int NWG = MT * NT;                 // 1536 / 512, both % 8 == 0

  __shared__ char lsA[128 * 128];   // [128 rows][64 bf16], XOR-swizzled within row
  __shared__ char lsB[128 * 128];
  const int tid = threadIdx.x;
  const int l = tid & 63, w = tid >> 6;
  const int wr = w >> 1, wc = w & 1;
  const int bid = blockIdx.x;
  const int swz = (bid & 7) * (NWG / 8) + (bid >> 3);
  const int bm = (swz % MT) * 128, bn = (swz / MT) * 128;
  const int row16 = l & 15, kg = l >> 4;

  f32x4 acc[4][4] = {};

  for (int k0 = 0; k0 < K; k0 += 64) {
    #pragma unroll
    for (int c = 0; c < 4; ++c) {
      const int o = c * 4096 + tid * 16;
      const int r = o >> 7;
      const int cb = (o & 127) ^ ((r & 7) << 4);
      gload_lds16((const char*)A + ((size_t)(bm + r) * K + k0) * 2 + cb,
                  lsA + c * 4096 + (w << 10));
      gload_lds16((const char*)Bw + ((size_t)(bn + r) * K + k0) * 2 + cb,
                  lsB + c * 4096 + (w << 10));
    }
    __syncthreads();

    #pragma unroll
    for (int h = 0; h < 2; ++h) {
      bf16x8 af[4], bfr[4];
      #pragma unroll
      for (int i = 0; i < 4; ++i) {
        const int ra = wr * 64 + i * 16 + row16;
        af[i]  = *(const bf16x8*)(lsA + ra * 128 + ((h * 64 + kg * 16) ^ ((ra & 7) << 4)));
        const int rb = wc * 64 + i * 16 + row16;
        bfr[i] = *(const bf16x8*)(lsB + rb * 128 + ((h * 64 + kg * 16) ^ ((rb & 7) << 4)));
      }
      #pragma unroll
      for (int i = 0; i < 4; ++i)
        #pragma unroll
        for (int j = 0; j < 4; ++j)
          acc[i][j] = mfma16(af[i], bfr[j], acc[i][j]);
    }
    __syncthreads();
  }

  // C/D layout: col = lane&15, row = (lane>>4)*4 + reg  [m89]
  const int r0 = kg * 4;
  #pragma unroll
  for (int i = 0; i < 4; ++i) {
    const int row = bm + wr * 64 + i * 16 + r0;
    #pragma unroll
    for (int j = 0; j < 4; ++j) {
      const int col = bn + wc * 64 + j * 16 + row16;
      const float bv = bias[col];
      if (EPI == 1) {
        #pragma unroll
        for (int r = 0; r < 4; ++r)
          c_out[(size_t)(row + r) * N + col] = acc[i][j][r] + bv;
      } else {
        const int sec = col >> 11;           // 0=Q 1=K 2=V
        const int within = col & 2047;
        const int head = within >> 7, d = within & 127;
        #pragma unroll
        for (int r = 0; r < 4; ++r) {
          const int rr = row + r;
          const int b = rr >> 11, s = rr & 2047;
          const int bh = b * NHEAD + head;
          const float v = acc[i][j][r] + bv;
          if (sec == 0)
            q_out[((size_t)bh * S_LEN + s) * DHEAD + d] = f2bf(v * QSCALE_L2E);
          else if (sec == 1)
            k_out[((size_t)bh * S_LEN + s) * DHEAD + d] = f2bf(v);
          else  // V stored transposed per head: Vt[bh][d][s]
            vt_out[((size_t)bh * DHEAD + d) * S_LEN + s] = f2bf(v);
        }
      }
    }
  }
}

// Causal flash attention: swapped QK^T, 32 q-rows/wave, 2-phase dbuf pipeline,
// T5 setprio around MFMA clusters. Grid: (16 q-tiles of 128 rows, 32 bh).
__global__ __launch_bounds__(256, 2) void attn_fwd(
    const unsigned short* __restrict__ Q, const unsigned short* __restrict__ Kk,
    const unsigned short* __restrict__ Vt, unsigned short* __restrict__ O)
{
  __shared__ char lsK[2][64 * 256];    // dbuf [64 kv][128 d] bf16, XOR-swizzled
  __shared__ char lsV[2][128 * 128];   // dbuf [128 d][64 kv] bf16, XOR-swizzled
  __shared__ char lsP[4][32 * 128];    // per-wave [32 q][64 kv] bf16, XOR-swizzled
  const int tid = threadIdx.x, l = tid & 63, w = tid >> 6;
  const int row16 = l & 15, kg = l >> 4;
  // complementary pairing: blocks i and i+256 get qb summing to 15
  const int qb = (blockIdx.y < 16) ? (15 - (int)blockIdx.x) : (int)blockIdx.x;
  const int bh = blockIdx.y;
  const int bidx = bh >> 4, head = bh & 15;

  const char* Qh = (const char*)(Q  + (size_t)bh * S_LEN * DHEAD);
  const char* Kh = (const char*)(Kk + (size_t)bh * S_LEN * DHEAD);
  const char* Vh = (const char*)(Vt + (size_t)bh * DHEAD * S_LEN);

  const int q0w = qb * 128 + w * 32;   // this wave's first q row

  bf16x8 qf[2][4];
  #pragma unroll
  for (int qs = 0; qs < 2; ++qs)
    #pragma unroll
    for (int t = 0; t < 4; ++t)
      qf[qs][t] = *(const bf16x8*)(Qh + ((size_t)(q0w + qs * 16 + row16) * DHEAD + t * 32 + kg * 8) * 2);

  float m[2]  = {-1e30f, -1e30f};
  float ls[2] = {0.f, 0.f};
  f32x4 oacc[2][8] = {};

  const int last = 2 * qb + 1;

#define STAGE(buf, kt_) do {                                                     \
    _Pragma("unroll")                                                            \
    for (int c = 0; c < 4; ++c) {                                                \
      const int o = c * 4096 + tid * 16;                                         \
      const int rk = o >> 8, cbk = (o & 255) ^ ((rk & 7) << 4);                  \
      gload_lds16(Kh + (size_t)((kt_) * 64 + rk) * 256 + cbk,                    \
                  lsK[buf] + c * 4096 + (w << 10));                              \
      const int dv = o >> 7, cbv = (o & 127) ^ ((dv & 7) << 4);                  \
      gload_lds16(Vh + (size_t)dv * 4096 + (size_t)(kt_) * 128 + cbv,            \
                  lsV[buf] + c * 4096 + (w << 10));                              \
    } } while (0)

  STAGE(0, 0);
  __syncthreads();

  int cur = 0;
  for (int kt = 0; ; ++kt) {
    if (kt < last) STAGE(cur ^ 1, kt + 1);   // prefetch next tile

    if (kt * 64 <= q0w + 31) {
      const char* Kc = lsK[cur];
      const char* Vc = lsV[cur];
      char* Pl = lsP[w];

      // ---- S^T = K Q^T
      f32x4 sc[4][2] = {};
      __builtin_amdgcn_s_setprio(1);
      #pragma unroll
      for (int j = 0; j < 4; ++j) {
        const int krow = j * 16 + row16;
        const int sw = (krow & 7) << 4;
        bf16x8 kf[4];
        #pragma unroll
        for (int t = 0; t < 4; ++t)
          kf[t] = *(const bf16x8*)(Kc + krow * 256 + ((t * 64 + kg * 16) ^ sw));
        #pragma unroll
        for (int t = 0; t < 4; ++t) {
          sc[j][0] = mfma16(kf[t], qf[0][t], sc[j][0]);
          sc[j][1] = mfma16(kf[t], qf[1][t], sc[j][1]);
        }
      }
      __builtin_amdgcn_s_setprio(0);

      if (kt >= 2 * qb) {  // causal mask on diagonal tiles
        #pragma unroll
        for (int j = 0; j < 4; ++j) {
          const int kvb = kt * 64 + j * 16 + kg * 4;
          #pragma unroll
          for (int qs = 0; qs < 2; ++qs) {
            const int qq = q0w + qs * 16 + row16;
            #pragma unroll
            for (int r = 0; r < 4; ++r)
              if (kvb + r > qq) sc[j][qs][r] = -1e30f;
          }
        }
      }

      // ---- online softmax (exp2 domain), defer-max (THR=8)
      float pm[2], al[2] = {1.f, 1.f};
      #pragma unroll
      for (int qs = 0; qs < 2; ++qs) {
        float mx = fmaxf(fmaxf(hmax4(sc[0][qs]), hmax4(sc[1][qs])),
                         fmaxf(hmax4(sc[2][qs]), hmax4(sc[3][qs])));
        mx = fmaxf(mx, __shfl_xor(mx, 16, 64));
        mx = fmaxf(mx, __shfl_xor(mx, 32, 64));
        pm[qs] = mx;
      }
      const bool need = (pm[0] > m[0] + 8.f) || (pm[1] > m[1] + 8.f);
      if (__any(need)) {
        const float n0 = fmaxf(m[0], pm[0]), n1 = fmaxf(m[1], pm[1]);
        al[0] = exp2f(m[0] - n0); al[1] = exp2f(m[1] - n1);
        m[0] = n0; m[1] = n1;
        float aq[2][4];
        #pragma unroll
        for (int qs2 = 0; qs2 < 2; ++qs2)
          #pragma unroll
          for (int r = 0; r < 4; ++r)
            aq[qs2][r] = __shfl(al[qs2], kg * 4 + r, 64);
        #pragma unroll
        for (int qs2 = 0; qs2 < 2; ++qs2)
          #pragma unroll
          for (int dt = 0; dt < 8; ++dt)
            #pragma unroll
            for (int r = 0; r < 4; ++r)
              oacc[qs2][dt][r] *= aq[qs2][r];
      }

      // ---- P = exp2(S - m) -> per-wave LDS (bf16, swizzled), row-sum
      #pragma unroll
      for (int qs = 0; qs < 2; ++qs) {
        const int q = qs * 16 + row16;
        const int psw = (q & 7) << 4;
        float ps = 0.f;
        #pragma unroll
        for (int j = 0; j < 4; ++j) {
          const float p0 = exp2f(sc[j][qs][0] - m[qs]);
          const float p1 = exp2f(sc[j][qs][1] - m[qs]);
          const float p2 = exp2f(sc[j][qs][2] - m[qs]);
          const float p3 = exp2f(sc[j][qs][3] - m[qs]);
          ps += (p0 + p1) + (p2 + p3);
          uint2 pw; pw.x = pkbf(p0, p1); pw.y = pkbf(p2, p3);
          *(uint2*)(Pl + q * 128 + ((j * 32 + kg * 8) ^ psw)) = pw;
        }
        ps += __shfl_xor(ps, 16, 64);
        ps += __shfl_xor(ps, 32, 64);
        ls[qs] = ls[qs] * al[qs] + ps;
      }

      // ---- O += P V
      bf16x8 pa[2][2];
      #pragma unroll
      for (int qs2 = 0; qs2 < 2; ++qs2) {
        const int q = qs2 * 16 + row16;
        #pragma unroll
        for (int ks = 0; ks < 2; ++ks)
          pa[qs2][ks] = *(const bf16x8*)(Pl + q * 128 + ((ks * 64 + kg * 16) ^ ((q & 7) << 4)));
      }
      __builtin_amdgcn_s_setprio(1);
      #pragma unroll
      for (int dt = 0; dt < 8; ++dt) {
        const int drow = dt * 16 + row16;
        const int vsw = (drow & 7) << 4;
        bf16x8 v0 = *(const bf16x8*)(Vc + drow * 128 + ((kg * 16) ^ vsw));
        bf16x8 v1 = *(const bf16x8*)(Vc + drow * 128 + ((64 + kg * 16) ^ vsw));
        oacc[0][dt] = mfma16(pa[0][0], v0, oacc[0][dt]);
        oacc[0][dt] = mfma16(pa[0][1], v1, oacc[0][dt]);
        oacc[1][dt] = mfma16(pa[1][0], v0, oacc[1][dt]);
        oacc[1][dt] = mfma16(pa[1][1], v1, oacc[1][dt]);
      }
      __builtin_amdgcn_s_setprio(0);
    }

    __syncthreads();   // drains prefetch (vmcnt) + joins waves before buffer swap
    if (kt == last) break;
    cur ^= 1;
  }
#undef STAGE

  // ---- epilogue: normalize rows, write O[b*S + q][head*128 + d] bf16
  #pragma unroll
  for (int qs2 = 0; qs2 < 2; ++qs2) {
    #pragma unroll
    for (int r = 0; r < 4; ++r) {
      const float lr = __shfl(ls[qs2], kg * 4 + r, 64);
      const float inv = 1.0f / lr;
      const int q = q0w + qs2 * 16 + kg * 4 + r;
      const size_t orow = (size_t)(bidx * S_LEN + q) * HID + (size_t)head * DHEAD;
      #pragma unroll
      for (int dt = 0; dt < 8; ++dt)
        O[orow + dt * 16 + row16] = f2bf(oacc[qs2][dt][r] * inv);
    }
  }
}

extern "C" void kernel_launch(void* const* d_in, const int* in_sizes, int n_in,
                              void* d_out, int out_size, void* d_ws, size_t ws_size,
                              hipStream_t stream) {
  const float* x    = (const float*)d_in[0];
  const float* Wqkv = (const float*)d_in[1];
  const float* bqkv = (const float*)d_in[2];
  const float* Wout = (const float*)d_in[3];
  const float* bout = (const float*)d_in[4];
  float* out = (float*)d_out;

  if (ws_size < 100663296) return;  // insufficient scratch -> clean validation fail
  char* ws = (char*)d_ws;
  unsigned short* Qb    = (unsigned short*)(ws);
  unsigned short* Kb    = (unsigned short*)(ws + 16777216);
  unsigned short* Vtb   = (unsigned short*)(ws + 2 * 16777216);
  unsigned short* xb    = (unsigned short*)(ws + 3 * 16777216);
  unsigned short* Ob    = xb;  // alias: xb dead after QKV GEMM, Ob written after
  unsigned short* Wqkvb = (unsigned short*)(ws + 4 * 16777216);
  unsigned short* Woutb = (unsigned short*)(ws + 4 * 16777216 + 25165824);

  cvt_bf16<<<2048, 256, 0, stream>>>(x,    xb,    4096 * 2048);
  cvt_bf16<<<2048, 256, 0, stream>>>(Wqkv, Wqkvb, 6144 * 2048);
  cvt_bf16<<<1024, 256, 0, stream>>>(Wout, Woutb, 2048 * 2048);

  // QKV: 32x48 tiles of 128^2 -> 1536 blocks (1D, XCD-chunked swizzle)
  gemm_bt<0><<<1536, 256, 0, stream>>>(xb, Wqkvb, bqkv, 2048, 6144,
                                       Qb, Kb, Vtb, nullptr);
  attn_fwd<<<dim3(16, 32), 256, 0, stream>>>(Qb, Kb, Vtb, Ob);
  // OUT: 32x16 tiles -> 512 blocks
  gemm_bt<1><<<512, 256, 0, stream>>>(Ob, Woutb, bout, 2048, 2048,
                                      nullptr, nullptr, nullptr, out);
}

// Round 9
// 282.930 us; speedup vs baseline: 1.1656x; 1.0652x over previous
//
#include <hip/hip_runtime.h>
#include <stdint.h>

// MHA fused: qkv-proj (bf16 MFMA GEMM) -> causal flash attn -> out-proj
// B=2, S=2048, H=2048, heads=16, D=128.
// Round-9: round-2 proven base (best measured: 284 us); Wout bf16 conversion
// folded into attn prologue as side-work (saves one launch + ~4 us of serial BW).

using bf16x8 = __attribute__((ext_vector_type(8))) __bf16;
using f32x4  = __attribute__((ext_vector_type(4))) float;

#define S_LEN 2048
#define HID   2048
#define NHEAD 16
#define DHEAD 128
// 1/sqrt(128) * log2(e): attention softmax runs in exp2 domain
#define QSCALE_L2E (0.08838834764831845f * 1.4426950408889634f)

__device__ __forceinline__ unsigned short f2bf(float f) {
  union { float f; unsigned int u; } c; c.f = f;
  unsigned int u = c.u;
  return (unsigned short)((u + 0x7FFFu + ((u >> 16) & 1u)) >> 16);  // RNE
}

__device__ __forceinline__ unsigned int pkbf(float a, float b) {
  union { __bf16 h[2]; unsigned int u; } x;
  x.h[0] = (__bf16)a; x.h[1] = (__bf16)b;
  return x.u;
}

__device__ __forceinline__ void gload_lds16(const void* g, void* l) {
  __builtin_amdgcn_global_load_lds(
      (const __attribute__((address_space(1))) unsigned int*)g,
      (__attribute__((address_space(3))) unsigned int*)l, 16, 0, 0);
}

__device__ __forceinline__ f32x4 mfma16(bf16x8 a, bf16x8 b, f32x4 c) {
  return __builtin_amdgcn_mfma_f32_16x16x32_bf16(a, b, c, 0, 0, 0);
}

__device__ __forceinline__ float hmax4(f32x4 v) {
  return fmaxf(fmaxf(v[0], v[1]), fmaxf(v[2], v[3]));
}

__global__ void cvt_bf16(const float* __restrict__ in, unsigned short* __restrict__ out, int n) {
  const int n4 = n >> 2;
  const int stride = gridDim.x * blockDim.x;
  for (int i = blockIdx.x * blockDim.x + threadIdx.x; i < n4; i += stride) {
    float4 v = reinterpret_cast<const float4*>(in)[i];
    ushort4 o;
    o.x = f2bf(v.x); o.y = f2bf(v.y); o.z = f2bf(v.z); o.w = f2bf(v.w);
    reinterpret_cast<ushort4*>(out)[i] = o;
  }
}

// C = A(M x K) * B(N x K)^T + bias.  128x128 tile, BK=64, 4 waves (2x2 of 64x64).
// EPI=0: scatter QKV epilogue (bf16).  EPI=1: fp32 row-major C.
// Natural dim3 grid (y-outer) — measured best L2 behavior (r8 showed XCD
// chunking REGRESSES here: operands are L3-resident, natural order shares
// B panels within the co-resident window).
template<int EPI>
__global__ __launch_bounds__(256) void gemm_bt(
    const unsigned short* __restrict__ A, const unsigned short* __restrict__ Bw,
    const float* __restrict__ bias, int K, int N,
    unsigned short* __restrict__ q_out, unsigned short* __restrict__ k_out,
    unsigned short* __restrict__ vt_out, float* __restrict__ c_out)
{
  __shared__ char lsA[128 * 128];   // [128 rows][64 bf16], XOR-swizzled within row
  __shared__ char lsB[128 * 128];
  const int tid = threadIdx.x;
  const int l = tid & 63, w = tid >> 6;
  const int wr = w >> 1, wc = w & 1;
  const int bm = blockIdx.x * 128, bn = blockIdx.y * 128;
  const int row16 = l & 15, kg = l >> 4;

  f32x4 acc[4][4] = {};

  for (int k0 = 0; k0 < K; k0 += 64) {
    #pragma unroll
    for (int c = 0; c < 4; ++c) {
      const int o = c * 4096 + tid * 16;
      const int r = o >> 7;
      const int cb = (o & 127) ^ ((r & 7) << 4);
      gload_lds16((const char*)A + ((size_t)(bm + r) * K + k0) * 2 + cb,
                  lsA + c * 4096 + (w << 10));
      gload_lds16((const char*)Bw + ((size_t)(bn + r) * K + k0) * 2 + cb,
                  lsB + c * 4096 + (w << 10));
    }
    __syncthreads();

    #pragma unroll
    for (int h = 0; h < 2; ++h) {
      bf16x8 af[4], bfr[4];
      #pragma unroll
      for (int i = 0; i < 4; ++i) {
        const int ra = wr * 64 + i * 16 + row16;
        af[i]  = *(const bf16x8*)(lsA + ra * 128 + ((h * 64 + kg * 16) ^ ((ra & 7) << 4)));
        const int rb = wc * 64 + i * 16 + row16;
        bfr[i] = *(const bf16x8*)(lsB + rb * 128 + ((h * 64 + kg * 16) ^ ((rb & 7) << 4)));
      }
      #pragma unroll
      for (int i = 0; i < 4; ++i)
        #pragma unroll
        for (int j = 0; j < 4; ++j)
          acc[i][j] = mfma16(af[i], bfr[j], acc[i][j]);
    }
    __syncthreads();
  }

  // C/D layout: col = lane&15, row = (lane>>4)*4 + reg  [m89]
  const int r0 = kg * 4;
  #pragma unroll
  for (int i = 0; i < 4; ++i) {
    const int row = bm + wr * 64 + i * 16 + r0;
    #pragma unroll
    for (int j = 0; j < 4; ++j) {
      const int col = bn + wc * 64 + j * 16 + row16;
      const float bv = bias[col];
      if (EPI == 1) {
        #pragma unroll
        for (int r = 0; r < 4; ++r)
          c_out[(size_t)(row + r) * N + col] = acc[i][j][r] + bv;
      } else {
        const int sec = col >> 11;           // 0=Q 1=K 2=V
        const int within = col & 2047;
        const int head = within >> 7, d = within & 127;
        #pragma unroll
        for (int r = 0; r < 4; ++r) {
          const int rr = row + r;
          const int b = rr >> 11, s = rr & 2047;
          const int bh = b * NHEAD + head;
          const float v = acc[i][j][r] + bv;
          if (sec == 0)
            q_out[((size_t)bh * S_LEN + s) * DHEAD + d] = f2bf(v * QSCALE_L2E);
          else if (sec == 1)
            k_out[((size_t)bh * S_LEN + s) * DHEAD + d] = f2bf(v);
          else  // V stored transposed per head: Vt[bh][d][s]
            vt_out[((size_t)bh * DHEAD + d) * S_LEN + s] = f2bf(v);
        }
      }
    }
  }
}

// Causal flash attention: swapped QK^T, 32 q-rows/wave, 2-phase dbuf pipeline.
// Grid: (16 q-tiles of 128 rows, 32 bh). Block: 4 waves.
// Side-work: each of the 512 blocks converts a 2048-float4 slice of Wout to
// bf16 during the first K/V stage (attn is far from BW-bound; saves a launch).
__global__ __launch_bounds__(256, 2) void attn_fwd(
    const unsigned short* __restrict__ Q, const unsigned short* __restrict__ Kk,
    const unsigned short* __restrict__ Vt, unsigned short* __restrict__ O,
    const float* __restrict__ Wout, unsigned short* __restrict__ Woutb)
{
  __shared__ char lsK[2][64 * 256];    // dbuf [64 kv][128 d] bf16, XOR-swizzled
  __shared__ char lsV[2][128 * 128];   // dbuf [128 d][64 kv] bf16, XOR-swizzled
  __shared__ char lsP[4][32 * 128];    // per-wave [32 q][64 kv] bf16, XOR-swizzled
  const int tid = threadIdx.x, l = tid & 63, w = tid >> 6;
  const int row16 = l & 15, kg = l >> 4;
  // complementary pairing: blocks i and i+256 get qb summing to 15 -> each CU's
  // two resident blocks have equal total kv-iterations (34)
  const int qb = (blockIdx.y < 16) ? (15 - (int)blockIdx.x) : (int)blockIdx.x;
  const int bh = blockIdx.y;
  const int bidx = bh >> 4, head = bh & 15;

  const char* Qh = (const char*)(Q  + (size_t)bh * S_LEN * DHEAD);
  const char* Kh = (const char*)(Kk + (size_t)bh * S_LEN * DHEAD);
  const char* Vh = (const char*)(Vt + (size_t)bh * DHEAD * S_LEN);

  const int q0w = qb * 128 + w * 32;   // this wave's first q row

  bf16x8 qf[2][4];
  #pragma unroll
  for (int qs = 0; qs < 2; ++qs)
    #pragma unroll
    for (int t = 0; t < 4; ++t)
      qf[qs][t] = *(const bf16x8*)(Qh + ((size_t)(q0w + qs * 16 + row16) * DHEAD + t * 32 + kg * 8) * 2);

  float m[2]  = {-1e30f, -1e30f};
  float ls[2] = {0.f, 0.f};
  f32x4 oacc[2][8] = {};

  const int last = 2 * qb + 1;

#define STAGE(buf, kt_) do {                                                     \
    _Pragma("unroll")                                                            \
    for (int c = 0; c < 4; ++c) {                                                \
      const int o = c * 4096 + tid * 16;                                         \
      const int rk = o >> 8, cbk = (o & 255) ^ ((rk & 7) << 4);                  \
      gload_lds16(Kh + (size_t)((kt_) * 64 + rk) * 256 + cbk,                    \
                  lsK[buf] + c * 4096 + (w << 10));                              \
      const int dv = o >> 7, cbv = (o & 127) ^ ((dv & 7) << 4);                  \
      gload_lds16(Vh + (size_t)dv * 4096 + (size_t)(kt_) * 128 + cbv,            \
                  lsV[buf] + c * 4096 + (w << 10));                              \
    } } while (0)

  STAGE(0, 0);

  // ---- Wout conversion side-work (overlaps first-tile stage latency)
  {
    const int slice = (int)blockIdx.y * 16 + (int)blockIdx.x;   // 0..511
    const float4* src = (const float4*)Wout;
    ushort4* dst = (ushort4*)Woutb;
    const int base = slice * 2048;   // 512 * 2048 float4 = 4M floats = Wout
    #pragma unroll
    for (int i = 0; i < 8; ++i) {
      float4 v = src[base + i * 256 + tid];
      ushort4 o;
      o.x = f2bf(v.x); o.y = f2bf(v.y); o.z = f2bf(v.z); o.w = f2bf(v.w);
      dst[base + i * 256 + tid] = o;
    }
  }

  __syncthreads();

  int cur = 0;
  for (int kt = 0; ; ++kt) {
    if (kt < last) STAGE(cur ^ 1, kt + 1);   // prefetch next tile

    // waves whose entire 32 q-rows are above this kv tile skip compute
    if (kt * 64 <= q0w + 31) {
      const char* Kc = lsK[cur];
      const char* Vc = lsV[cur];
      char* Pl = lsP[w];

      // ---- S^T = K Q^T
      f32x4 sc[4][2] = {};
      #pragma unroll
      for (int j = 0; j < 4; ++j) {
        const int krow = j * 16 + row16;
        const int sw = (krow & 7) << 4;
        bf16x8 kf[4];
        #pragma unroll
        for (int t = 0; t < 4; ++t)
          kf[t] = *(const bf16x8*)(Kc + krow * 256 + ((t * 64 + kg * 16) ^ sw));
        #pragma unroll
        for (int t = 0; t < 4; ++t) {
          sc[j][0] = mfma16(kf[t], qf[0][t], sc[j][0]);
          sc[j][1] = mfma16(kf[t], qf[1][t], sc[j][1]);
        }
      }

      if (kt >= 2 * qb) {  // causal mask on diagonal tiles
        #pragma unroll
        for (int j = 0; j < 4; ++j) {
          const int kvb = kt * 64 + j * 16 + kg * 4;
          #pragma unroll
          for (int qs = 0; qs < 2; ++qs) {
            const int qq = q0w + qs * 16 + row16;
            #pragma unroll
            for (int r = 0; r < 4; ++r)
              if (kvb + r > qq) sc[j][qs][r] = -1e30f;
          }
        }
      }

      // ---- online softmax (exp2 domain), defer-max (THR=8)
      float pm[2], al[2] = {1.f, 1.f};
      #pragma unroll
      for (int qs = 0; qs < 2; ++qs) {
        float mx = fmaxf(fmaxf(hmax4(sc[0][qs]), hmax4(sc[1][qs])),
                         fmaxf(hmax4(sc[2][qs]), hmax4(sc[3][qs])));
        mx = fmaxf(mx, __shfl_xor(mx, 16, 64));
        mx = fmaxf(mx, __shfl_xor(mx, 32, 64));
        pm[qs] = mx;
      }
      const bool need = (pm[0] > m[0] + 8.f) || (pm[1] > m[1] + 8.f);
      if (__any(need)) {
        const float n0 = fmaxf(m[0], pm[0]), n1 = fmaxf(m[1], pm[1]);
        al[0] = exp2f(m[0] - n0); al[1] = exp2f(m[1] - n1);
        m[0] = n0; m[1] = n1;
        float aq[2][4];
        #pragma unroll
        for (int qs2 = 0; qs2 < 2; ++qs2)
          #pragma unroll
          for (int r = 0; r < 4; ++r)
            aq[qs2][r] = __shfl(al[qs2], kg * 4 + r, 64);
        #pragma unroll
        for (int qs2 = 0; qs2 < 2; ++qs2)
          #pragma unroll
          for (int dt = 0; dt < 8; ++dt)
            #pragma unroll
            for (int r = 0; r < 4; ++r)
              oacc[qs2][dt][r] *= aq[qs2][r];
      }

      // ---- P = exp2(S - m) -> per-wave LDS (bf16, swizzled), row-sum
      #pragma unroll
      for (int qs = 0; qs < 2; ++qs) {
        const int q = qs * 16 + row16;
        const int psw = (q & 7) << 4;
        float ps = 0.f;
        #pragma unroll
        for (int j = 0; j < 4; ++j) {
          const float p0 = exp2f(sc[j][qs][0] - m[qs]);
          const float p1 = exp2f(sc[j][qs][1] - m[qs]);
          const float p2 = exp2f(sc[j][qs][2] - m[qs]);
          const float p3 = exp2f(sc[j][qs][3] - m[qs]);
          ps += (p0 + p1) + (p2 + p3);
          uint2 pw; pw.x = pkbf(p0, p1); pw.y = pkbf(p2, p3);
          *(uint2*)(Pl + q * 128 + ((j * 32 + kg * 8) ^ psw)) = pw;
        }
        ps += __shfl_xor(ps, 16, 64);
        ps += __shfl_xor(ps, 32, 64);
        ls[qs] = ls[qs] * al[qs] + ps;
      }

      // ---- O += P V  (A = P rows q, B = Vt rows d)
      bf16x8 pa[2][2];
      #pragma unroll
      for (int qs2 = 0; qs2 < 2; ++qs2) {
        const int q = qs2 * 16 + row16;
        #pragma unroll
        for (int ks = 0; ks < 2; ++ks)
          pa[qs2][ks] = *(const bf16x8*)(Pl + q * 128 + ((ks * 64 + kg * 16) ^ ((q & 7) << 4)));
      }
      #pragma unroll
      for (int dt = 0; dt < 8; ++dt) {
        const int drow = dt * 16 + row16;
        const int vsw = (drow & 7) << 4;
        bf16x8 v0 = *(const bf16x8*)(Vc + drow * 128 + ((kg * 16) ^ vsw));
        bf16x8 v1 = *(const bf16x8*)(Vc + drow * 128 + ((64 + kg * 16) ^ vsw));
        oacc[0][dt] = mfma16(pa[0][0], v0, oacc[0][dt]);
        oacc[0][dt] = mfma16(pa[0][1], v1, oacc[0][dt]);
        oacc[1][dt] = mfma16(pa[1][0], v0, oacc[1][dt]);
        oacc[1][dt] = mfma16(pa[1][1], v1, oacc[1][dt]);
      }
    }

    __syncthreads();   // drains prefetch (vmcnt) + joins waves before buffer swap
    if (kt == last) break;
    cur ^= 1;
  }
#undef STAGE

  // ---- epilogue: normalize rows, write O[b*S + q][head*128 + d] bf16
  #pragma unroll
  for (int qs2 = 0; qs2 < 2; ++qs2) {
    #pragma unroll
    for (int r = 0; r < 4; ++r) {
      const float lr = __shfl(ls[qs2], kg * 4 + r, 64);
      const float inv = 1.0f / lr;
      const int q = q0w + qs2 * 16 + kg * 4 + r;
      const size_t orow = (size_t)(bidx * S_LEN + q) * HID + (size_t)head * DHEAD;
      #pragma unroll
      for (int dt = 0; dt < 8; ++dt)
        O[orow + dt * 16 + row16] = f2bf(oacc[qs2][dt][r] * inv);
    }
  }
}

extern "C" void kernel_launch(void* const* d_in, const int* in_sizes, int n_in,
                              void* d_out, int out_size, void* d_ws, size_t ws_size,
                              hipStream_t stream) {
  const float* x    = (const float*)d_in[0];
  const float* Wqkv = (const float*)d_in[1];
  const float* bqkv = (const float*)d_in[2];
  const float* Wout = (const float*)d_in[3];
  const float* bout = (const float*)d_in[4];
  float* out = (float*)d_out;

  if (ws_size < 100663296) return;  // insufficient scratch -> clean validation fail
  char* ws = (char*)d_ws;
  unsigned short* Qb    = (unsigned short*)(ws);
  unsigned short* Kb    = (unsigned short*)(ws + 16777216);
  unsigned short* Vtb   = (unsigned short*)(ws + 2 * 16777216);
  unsigned short* xb    = (unsigned short*)(ws + 3 * 16777216);
  unsigned short* Ob    = xb;  // alias: xb dead after QKV GEMM, Ob written after
  unsigned short* Wqkvb = (unsigned short*)(ws + 4 * 16777216);
  unsigned short* Woutb = (unsigned short*)(ws + 4 * 16777216 + 25165824);

  cvt_bf16<<<2048, 256, 0, stream>>>(x,    xb,    4096 * 2048);
  cvt_bf16<<<2048, 256, 0, stream>>>(Wqkv, Wqkvb, 6144 * 2048);
  // Wout conversion is folded into attn_fwd's prologue side-work.

  gemm_bt<0><<<dim3(32, 48), 256, 0, stream>>>(xb, Wqkvb, bqkv, 2048, 6144,
                                               Qb, Kb, Vtb, nullptr);
  attn_fwd<<<dim3(16, 32), 256, 0, stream>>>(Qb, Kb, Vtb, Ob, Wout, Woutb);
  gemm_bt<1><<<dim3(32, 16), 256, 0, stream>>>(Ob, Woutb, bout, 2048, 2048,
                                               nullptr, nullptr, nullptr, out);
}

// Round 10
// 264.392 us; speedup vs baseline: 1.2473x; 1.0701x over previous
//
#include <hip/hip_runtime.h>
#include <stdint.h>

// MHA fused: qkv-proj (bf16 MFMA GEMM) -> causal flash attn -> out-proj
// B=2, S=2048, H=2048, heads=16, D=128.
// Round-10: round-9 base + coalesced LDS-staged epilogues (WRITE_SIZE 50->26MB
// on QKV, 50->36MB on out-proj) + merged cvt launch.

using bf16x8 = __attribute__((ext_vector_type(8))) __bf16;
using f32x4  = __attribute__((ext_vector_type(4))) float;

#define S_LEN 2048
#define HID   2048
#define NHEAD 16
#define DHEAD 128
// 1/sqrt(128) * log2(e): attention softmax runs in exp2 domain
#define QSCALE_L2E (0.08838834764831845f * 1.4426950408889634f)

__device__ __forceinline__ unsigned short f2bf(float f) {
  union { float f; unsigned int u; } c; c.f = f;
  unsigned int u = c.u;
  return (unsigned short)((u + 0x7FFFu + ((u >> 16) & 1u)) >> 16);  // RNE
}

__device__ __forceinline__ unsigned int pkbf(float a, float b) {
  union { __bf16 h[2]; unsigned int u; } x;
  x.h[0] = (__bf16)a; x.h[1] = (__bf16)b;
  return x.u;
}

__device__ __forceinline__ void gload_lds16(const void* g, void* l) {
  __builtin_amdgcn_global_load_lds(
      (const __attribute__((address_space(1))) unsigned int*)g,
      (__attribute__((address_space(3))) unsigned int*)l, 16, 0, 0);
}

__device__ __forceinline__ f32x4 mfma16(bf16x8 a, bf16x8 b, f32x4 c) {
  return __builtin_amdgcn_mfma_f32_16x16x32_bf16(a, b, c, 0, 0, 0);
}

__device__ __forceinline__ float hmax4(f32x4 v) {
  return fmaxf(fmaxf(v[0], v[1]), fmaxf(v[2], v[3]));
}

// merged conversion: x -> xb, Wqkv -> Wqkvb in one launch
__global__ void cvt_two(const float* __restrict__ a, unsigned short* __restrict__ ao, int na4,
                        const float* __restrict__ b, unsigned short* __restrict__ bo, int nb4) {
  const int stride = gridDim.x * blockDim.x;
  const int tot = na4 + nb4;
  for (int i = blockIdx.x * blockDim.x + threadIdx.x; i < tot; i += stride) {
    const float4* src; ushort4* dst; int idx;
    if (i < na4) { src = (const float4*)a; dst = (ushort4*)ao; idx = i; }
    else         { src = (const float4*)b; dst = (ushort4*)bo; idx = i - na4; }
    float4 v = src[idx];
    ushort4 o;
    o.x = f2bf(v.x); o.y = f2bf(v.y); o.z = f2bf(v.z); o.w = f2bf(v.w);
    dst[idx] = o;
  }
}

// C = A(M x K) * B(N x K)^T + bias.  128x128 tile, BK=64, 4 waves (2x2 of 64x64).
// EPI=0: QKV scatter epilogue (bf16).  EPI=1: fp32 row-major C.
// Natural dim3 grid (y-outer) — measured best L2 behavior (r8: XCD chunking
// regresses here; operands are L3-resident).
// Epilogues stage C through the (dead) 32KB LDS buffer in output-major layout
// and copy out with 16B/lane linear stores -> fully coalesced global writes.
template<int EPI>
__global__ __launch_bounds__(256) void gemm_bt(
    const unsigned short* __restrict__ A, const unsigned short* __restrict__ Bw,
    const float* __restrict__ bias, int K, int N,
    unsigned short* __restrict__ q_out, unsigned short* __restrict__ k_out,
    unsigned short* __restrict__ vt_out, float* __restrict__ c_out)
{
  __shared__ __align__(16) char lds[32768];
  char* lsA = lds;            // [128 rows][64 bf16], XOR-swizzled within row
  char* lsB = lds + 16384;
  const int tid = threadIdx.x;
  const int l = tid & 63, w = tid >> 6;
  const int wr = w >> 1, wc = w & 1;
  const int bm = blockIdx.x * 128, bn = blockIdx.y * 128;
  const int row16 = l & 15, kg = l >> 4;

  f32x4 acc[4][4] = {};

  for (int k0 = 0; k0 < K; k0 += 64) {
    #pragma unroll
    for (int c = 0; c < 4; ++c) {
      const int o = c * 4096 + tid * 16;
      const int r = o >> 7;
      const int cb = (o & 127) ^ ((r & 7) << 4);
      gload_lds16((const char*)A + ((size_t)(bm + r) * K + k0) * 2 + cb,
                  lsA + c * 4096 + (w << 10));
      gload_lds16((const char*)Bw + ((size_t)(bn + r) * K + k0) * 2 + cb,
                  lsB + c * 4096 + (w << 10));
    }
    __syncthreads();

    #pragma unroll
    for (int h = 0; h < 2; ++h) {
      bf16x8 af[4], bfr[4];
      #pragma unroll
      for (int i = 0; i < 4; ++i) {
        const int ra = wr * 64 + i * 16 + row16;
        af[i]  = *(const bf16x8*)(lsA + ra * 128 + ((h * 64 + kg * 16) ^ ((ra & 7) << 4)));
        const int rb = wc * 64 + i * 16 + row16;
        bfr[i] = *(const bf16x8*)(lsB + rb * 128 + ((h * 64 + kg * 16) ^ ((rb & 7) << 4)));
      }
      #pragma unroll
      for (int i = 0; i < 4; ++i)
        #pragma unroll
        for (int j = 0; j < 4; ++j)
          acc[i][j] = mfma16(af[i], bfr[j], acc[i][j]);
    }
    __syncthreads();   // also frees lds for the epilogue staging below
  }

  // C/D layout: col = lane&15, row = (lane>>4)*4 + reg  [m89]
  if (EPI == 1) {
    // fp32 out: two 64-row passes through LDS [64][512B], then coalesced copy.
    #pragma unroll
    for (int p = 0; p < 2; ++p) {
      if (wr == p) {
        #pragma unroll
        for (int i = 0; i < 4; ++i) {
          #pragma unroll
          for (int j = 0; j < 4; ++j) {
            const int c = wc * 64 + j * 16 + row16;
            const float bv = bias[bn + c];
            #pragma unroll
            for (int r = 0; r < 4; ++r) {
              const int Rl = i * 16 + kg * 4 + r;   // local row within half
              *(float*)(lds + Rl * 512 + ((c * 4) ^ ((Rl & 7) << 4))) = acc[i][j][r] + bv;
            }
          }
        }
      }
      __syncthreads();
      #pragma unroll
      for (int it = 0; it < 8; ++it) {
        const int o = it * 4096 + tid * 16;
        const int rw = o >> 9, cb = o & 511;
        uint4 v = *(const uint4*)(lds + rw * 512 + (cb ^ ((rw & 7) << 4)));
        *(uint4*)((char*)c_out + ((size_t)(bm + p * 64 + rw) * N + bn) * 4 + cb) = v;
      }
      __syncthreads();
    }
  } else {
    // QKV scatter: each block covers exactly one (sec, head, b); tile is a
    // contiguous [128 s][128 d] region for Q/K, [128 d][128 s] for Vt.
    const int secb  = bn >> 11;            // 0=Q 1=K 2=V (constant per block)
    const int headb = (bn & 2047) >> 7;
    const int s0    = bm & 2047;
    const int bh    = (bm >> 11) * NHEAD + headb;

    if (secb < 2) {
      // LDS [s 128][d 128] bf16, row-swizzled; b16 writes (<=4-way, one-shot)
      #pragma unroll
      for (int i = 0; i < 4; ++i) {
        const int R0 = wr * 64 + i * 16 + kg * 4;
        #pragma unroll
        for (int j = 0; j < 4; ++j) {
          const int c = wc * 64 + j * 16 + row16;
          const float bv = bias[bn + c];
          #pragma unroll
          for (int r = 0; r < 4; ++r) {
            float v = acc[i][j][r] + bv;
            if (secb == 0) v *= QSCALE_L2E;
            const int Rr = R0 + r;
            *(unsigned short*)(lds + Rr * 256 + ((c * 2) ^ ((Rr & 7) << 4))) = f2bf(v);
          }
        }
      }
      __syncthreads();
      unsigned short* qk = (secb == 0) ? q_out : k_out;
      char* gbase = (char*)(qk + ((size_t)bh * S_LEN + s0) * DHEAD);
      #pragma unroll
      for (int it = 0; it < 8; ++it) {
        const int o = it * 4096 + tid * 16;
        const int s = o >> 8, db = o & 255;
        uint4 v = *(const uint4*)(lds + s * 256 + (db ^ ((s & 7) << 4)));
        *(uint4*)(gbase + (size_t)s * 256 + db) = v;
      }
    } else {
      // Vt: LDS [d 128][s 128] bf16; lane packs its 4 consecutive s -> b64 write
      #pragma unroll
      for (int i = 0; i < 4; ++i) {
        const int R0 = wr * 64 + i * 16 + kg * 4;   // s base (4 consecutive)
        #pragma unroll
        for (int j = 0; j < 4; ++j) {
          const int c = wc * 64 + j * 16 + row16;   // d
          const float bv = bias[bn + c];
          uint2 pw;
          pw.x = pkbf(acc[i][j][0] + bv, acc[i][j][1] + bv);
          pw.y = pkbf(acc[i][j][2] + bv, acc[i][j][3] + bv);
          *(uint2*)(lds + c * 256 + ((R0 * 2) ^ ((c & 7) << 4))) = pw;
        }
      }
      __syncthreads();
      char* gbase = (char*)vt_out + ((size_t)bh * DHEAD) * (S_LEN * 2) + (size_t)s0 * 2;
      #pragma unroll
      for (int it = 0; it < 8; ++it) {
        const int o = it * 4096 + tid * 16;
        const int d = o >> 8, sb = o & 255;
        uint4 v = *(const uint4*)(lds + d * 256 + (sb ^ ((d & 7) << 4)));
        *(uint4*)(gbase + (size_t)d * (S_LEN * 2) + sb) = v;
      }
    }
  }
}

// Causal flash attention: swapped QK^T, 32 q-rows/wave, 2-phase dbuf pipeline.
// Grid: (16 q-tiles of 128 rows, 32 bh). Block: 4 waves.
// Side-work: each of the 512 blocks converts a slice of Wout to bf16 during
// the first K/V stage.
__global__ __launch_bounds__(256, 2) void attn_fwd(
    const unsigned short* __restrict__ Q, const unsigned short* __restrict__ Kk,
    const unsigned short* __restrict__ Vt, unsigned short* __restrict__ O,
    const float* __restrict__ Wout, unsigned short* __restrict__ Woutb)
{
  __shared__ char lsK[2][64 * 256];    // dbuf [64 kv][128 d] bf16, XOR-swizzled
  __shared__ char lsV[2][128 * 128];   // dbuf [128 d][64 kv] bf16, XOR-swizzled
  __shared__ char lsP[4][32 * 128];    // per-wave [32 q][64 kv] bf16, XOR-swizzled
  const int tid = threadIdx.x, l = tid & 63, w = tid >> 6;
  const int row16 = l & 15, kg = l >> 4;
  const int qb = (blockIdx.y < 16) ? (15 - (int)blockIdx.x) : (int)blockIdx.x;
  const int bh = blockIdx.y;
  const int bidx = bh >> 4, head = bh & 15;

  const char* Qh = (const char*)(Q  + (size_t)bh * S_LEN * DHEAD);
  const char* Kh = (const char*)(Kk + (size_t)bh * S_LEN * DHEAD);
  const char* Vh = (const char*)(Vt + (size_t)bh * DHEAD * S_LEN);

  const int q0w = qb * 128 + w * 32;   // this wave's first q row

  bf16x8 qf[2][4];
  #pragma unroll
  for (int qs = 0; qs < 2; ++qs)
    #pragma unroll
    for (int t = 0; t < 4; ++t)
      qf[qs][t] = *(const bf16x8*)(Qh + ((size_t)(q0w + qs * 16 + row16) * DHEAD + t * 32 + kg * 8) * 2);

  float m[2]  = {-1e30f, -1e30f};
  float ls[2] = {0.f, 0.f};
  f32x4 oacc[2][8] = {};

  const int last = 2 * qb + 1;

#define STAGE(buf, kt_) do {                                                     \
    _Pragma("unroll")                                                            \
    for (int c = 0; c < 4; ++c) {                                                \
      const int o = c * 4096 + tid * 16;                                         \
      const int rk = o >> 8, cbk = (o & 255) ^ ((rk & 7) << 4);                  \
      gload_lds16(Kh + (size_t)((kt_) * 64 + rk) * 256 + cbk,                    \
                  lsK[buf] + c * 4096 + (w << 10));                              \
      const int dv = o >> 7, cbv = (o & 127) ^ ((dv & 7) << 4);                  \
      gload_lds16(Vh + (size_t)dv * 4096 + (size_t)(kt_) * 128 + cbv,            \
                  lsV[buf] + c * 4096 + (w << 10));                              \
    } } while (0)

  STAGE(0, 0);

  // ---- Wout conversion side-work (overlaps first-tile stage latency)
  {
    const int slice = (int)blockIdx.y * 16 + (int)blockIdx.x;   // 0..511
    const float4* src = (const float4*)Wout;
    ushort4* dst = (ushort4*)Woutb;
    const int base = slice * 2048;   // 512 * 2048 float4 = Wout (4M floats)
    #pragma unroll
    for (int i = 0; i < 8; ++i) {
      float4 v = src[base + i * 256 + tid];
      ushort4 o;
      o.x = f2bf(v.x); o.y = f2bf(v.y); o.z = f2bf(v.z); o.w = f2bf(v.w);
      dst[base + i * 256 + tid] = o;
    }
  }

  __syncthreads();

  int cur = 0;
  for (int kt = 0; ; ++kt) {
    if (kt < last) STAGE(cur ^ 1, kt + 1);   // prefetch next tile

    if (kt * 64 <= q0w + 31) {
      const char* Kc = lsK[cur];
      const char* Vc = lsV[cur];
      char* Pl = lsP[w];

      // ---- S^T = K Q^T
      f32x4 sc[4][2] = {};
      #pragma unroll
      for (int j = 0; j < 4; ++j) {
        const int krow = j * 16 + row16;
        const int sw = (krow & 7) << 4;
        bf16x8 kf[4];
        #pragma unroll
        for (int t = 0; t < 4; ++t)
          kf[t] = *(const bf16x8*)(Kc + krow * 256 + ((t * 64 + kg * 16) ^ sw));
        #pragma unroll
        for (int t = 0; t < 4; ++t) {
          sc[j][0] = mfma16(kf[t], qf[0][t], sc[j][0]);
          sc[j][1] = mfma16(kf[t], qf[1][t], sc[j][1]);
        }
      }

      if (kt >= 2 * qb) {  // causal mask on diagonal tiles
        #pragma unroll
        for (int j = 0; j < 4; ++j) {
          const int kvb = kt * 64 + j * 16 + kg * 4;
          #pragma unroll
          for (int qs = 0; qs < 2; ++qs) {
            const int qq = q0w + qs * 16 + row16;
            #pragma unroll
            for (int r = 0; r < 4; ++r)
              if (kvb + r > qq) sc[j][qs][r] = -1e30f;
          }
        }
      }

      // ---- online softmax (exp2 domain), defer-max (THR=8)
      float pm[2], al[2] = {1.f, 1.f};
      #pragma unroll
      for (int qs = 0; qs < 2; ++qs) {
        float mx = fmaxf(fmaxf(hmax4(sc[0][qs]), hmax4(sc[1][qs])),
                         fmaxf(hmax4(sc[2][qs]), hmax4(sc[3][qs])));
        mx = fmaxf(mx, __shfl_xor(mx, 16, 64));
        mx = fmaxf(mx, __shfl_xor(mx, 32, 64));
        pm[qs] = mx;
      }
      const bool need = (pm[0] > m[0] + 8.f) || (pm[1] > m[1] + 8.f);
      if (__any(need)) {
        const float n0 = fmaxf(m[0], pm[0]), n1 = fmaxf(m[1], pm[1]);
        al[0] = exp2f(m[0] - n0); al[1] = exp2f(m[1] - n1);
        m[0] = n0; m[1] = n1;
        float aq[2][4];
        #pragma unroll
        for (int qs2 = 0; qs2 < 2; ++qs2)
          #pragma unroll
          for (int r = 0; r < 4; ++r)
            aq[qs2][r] = __shfl(al[qs2], kg * 4 + r, 64);
        #pragma unroll
        for (int qs2 = 0; qs2 < 2; ++qs2)
          #pragma unroll
          for (int dt = 0; dt < 8; ++dt)
            #pragma unroll
            for (int r = 0; r < 4; ++r)
              oacc[qs2][dt][r] *= aq[qs2][r];
      }

      // ---- P = exp2(S - m) -> per-wave LDS (bf16, swizzled), row-sum
      #pragma unroll
      for (int qs = 0; qs < 2; ++qs) {
        const int q = qs * 16 + row16;
        const int psw = (q & 7) << 4;
        float ps = 0.f;
        #pragma unroll
        for (int j = 0; j < 4; ++j) {
          const float p0 = exp2f(sc[j][qs][0] - m[qs]);
          const float p1 = exp2f(sc[j][qs][1] - m[qs]);
          const float p2 = exp2f(sc[j][qs][2] - m[qs]);
          const float p3 = exp2f(sc[j][qs][3] - m[qs]);
          ps += (p0 + p1) + (p2 + p3);
          uint2 pw; pw.x = pkbf(p0, p1); pw.y = pkbf(p2, p3);
          *(uint2*)(Pl + q * 128 + ((j * 32 + kg * 8) ^ psw)) = pw;
        }
        ps += __shfl_xor(ps, 16, 64);
        ps += __shfl_xor(ps, 32, 64);
        ls[qs] = ls[qs] * al[qs] + ps;
      }

      // ---- O += P V  (A = P rows q, B = Vt rows d)
      bf16x8 pa[2][2];
      #pragma unroll
      for (int qs2 = 0; qs2 < 2; ++qs2) {
        const int q = qs2 * 16 + row16;
        #pragma unroll
        for (int ks = 0; ks < 2; ++ks)
          pa[qs2][ks] = *(const bf16x8*)(Pl + q * 128 + ((ks * 64 + kg * 16) ^ ((q & 7) << 4)));
      }
      #pragma unroll
      for (int dt = 0; dt < 8; ++dt) {
        const int drow = dt * 16 + row16;
        const int vsw = (drow & 7) << 4;
        bf16x8 v0 = *(const bf16x8*)(Vc + drow * 128 + ((kg * 16) ^ vsw));
        bf16x8 v1 = *(const bf16x8*)(Vc + drow * 128 + ((64 + kg * 16) ^ vsw));
        oacc[0][dt] = mfma16(pa[0][0], v0, oacc[0][dt]);
        oacc[0][dt] = mfma16(pa[0][1], v1, oacc[0][dt]);
        oacc[1][dt] = mfma16(pa[1][0], v0, oacc[1][dt]);
        oacc[1][dt] = mfma16(pa[1][1], v1, oacc[1][dt]);
      }
    }

    __syncthreads();   // drains prefetch (vmcnt) + joins waves before buffer swap
    if (kt == last) break;
    cur ^= 1;
  }
#undef STAGE

  // ---- epilogue: normalize rows, write O[b*S + q][head*128 + d] bf16
  #pragma unroll
  for (int qs2 = 0; qs2 < 2; ++qs2) {
    #pragma unroll
    for (int r = 0; r < 4; ++r) {
      const float lr = __shfl(ls[qs2], kg * 4 + r, 64);
      const float inv = 1.0f / lr;
      const int q = q0w + qs2 * 16 + kg * 4 + r;
      const size_t orow = (size_t)(bidx * S_LEN + q) * HID + (size_t)head * DHEAD;
      #pragma unroll
      for (int dt = 0; dt < 8; ++dt)
        O[orow + dt * 16 + row16] = f2bf(oacc[qs2][dt][r] * inv);
    }
  }
}

extern "C" void kernel_launch(void* const* d_in, const int* in_sizes, int n_in,
                              void* d_out, int out_size, void* d_ws, size_t ws_size,
                              hipStream_t stream) {
  const float* x    = (const float*)d_in[0];
  const float* Wqkv = (const float*)d_in[1];
  const float* bqkv = (const float*)d_in[2];
  const float* Wout = (const float*)d_in[3];
  const float* bout = (const float*)d_in[4];
  float* out = (float*)d_out;

  if (ws_size < 100663296) return;  // insufficient scratch -> clean validation fail
  char* ws = (char*)d_ws;
  unsigned short* Qb    = (unsigned short*)(ws);
  unsigned short* Kb    = (unsigned short*)(ws + 16777216);
  unsigned short* Vtb   = (unsigned short*)(ws + 2 * 16777216);
  unsigned short* xb    = (unsigned short*)(ws + 3 * 16777216);
  unsigned short* Ob    = xb;  // alias: xb dead after QKV GEMM, Ob written after
  unsigned short* Wqkvb = (unsigned short*)(ws + 4 * 16777216);
  unsigned short* Woutb = (unsigned short*)(ws + 4 * 16777216 + 25165824);

  // x + Wqkv conversion in one launch; Wout conversion folded into attn_fwd.
  cvt_two<<<2048, 256, 0, stream>>>(x, xb, 4096 * 2048 / 4,
                                    Wqkv, Wqkvb, 6144 * 2048 / 4);

  gemm_bt<0><<<dim3(32, 48), 256, 0, stream>>>(xb, Wqkvb, bqkv, 2048, 6144,
                                               Qb, Kb, Vtb, nullptr);
  attn_fwd<<<dim3(16, 32), 256, 0, stream>>>(Qb, Kb, Vtb, Ob, Wout, Woutb);
  gemm_bt<1><<<dim3(32, 16), 256, 0, stream>>>(Ob, Woutb, bout, 2048, 2048,
                                               nullptr, nullptr, nullptr, out);
}

// Round 11
// 255.361 us; speedup vs baseline: 1.2914x; 1.0354x over previous
//
#include <hip/hip_runtime.h>
#include <stdint.h>

// MHA fused: qkv-proj (bf16 MFMA GEMM) -> causal flash attn -> out-proj
// B=2, S=2048, H=2048, heads=16, D=128.
// Round-11: r10 base, GEMMs switched 16x16x32 -> 32x32x16 MFMA (2382 vs 2075 TF
// ubench, LDS-neutral at 64x64 wave tile). Attn/cvt/epilogue-copyout unchanged.

using bf16x8 = __attribute__((ext_vector_type(8))) __bf16;
using f32x4  = __attribute__((ext_vector_type(4))) float;
using f32x16 = __attribute__((ext_vector_type(16))) float;

#define S_LEN 2048
#define HID   2048
#define NHEAD 16
#define DHEAD 128
// 1/sqrt(128) * log2(e): attention softmax runs in exp2 domain
#define QSCALE_L2E (0.08838834764831845f * 1.4426950408889634f)

__device__ __forceinline__ unsigned short f2bf(float f) {
  union { float f; unsigned int u; } c; c.f = f;
  unsigned int u = c.u;
  return (unsigned short)((u + 0x7FFFu + ((u >> 16) & 1u)) >> 16);  // RNE
}

__device__ __forceinline__ unsigned int pkbf(float a, float b) {
  union { __bf16 h[2]; unsigned int u; } x;
  x.h[0] = (__bf16)a; x.h[1] = (__bf16)b;
  return x.u;
}

__device__ __forceinline__ void gload_lds16(const void* g, void* l) {
  __builtin_amdgcn_global_load_lds(
      (const __attribute__((address_space(1))) unsigned int*)g,
      (__attribute__((address_space(3))) unsigned int*)l, 16, 0, 0);
}

__device__ __forceinline__ f32x4 mfma16(bf16x8 a, bf16x8 b, f32x4 c) {
  return __builtin_amdgcn_mfma_f32_16x16x32_bf16(a, b, c, 0, 0, 0);
}

__device__ __forceinline__ f32x16 mfma32(bf16x8 a, bf16x8 b, f32x16 c) {
  return __builtin_amdgcn_mfma_f32_32x32x16_bf16(a, b, c, 0, 0, 0);
}

__device__ __forceinline__ float hmax4(f32x4 v) {
  return fmaxf(fmaxf(v[0], v[1]), fmaxf(v[2], v[3]));
}

// merged conversion: x -> xb, Wqkv -> Wqkvb in one launch
__global__ void cvt_two(const float* __restrict__ a, unsigned short* __restrict__ ao, int na4,
                        const float* __restrict__ b, unsigned short* __restrict__ bo, int nb4) {
  const int stride = gridDim.x * blockDim.x;
  const int tot = na4 + nb4;
  for (int i = blockIdx.x * blockDim.x + threadIdx.x; i < tot; i += stride) {
    const float4* src; ushort4* dst; int idx;
    if (i < na4) { src = (const float4*)a; dst = (ushort4*)ao; idx = i; }
    else         { src = (const float4*)b; dst = (ushort4*)bo; idx = i - na4; }
    float4 v = src[idx];
    ushort4 o;
    o.x = f2bf(v.x); o.y = f2bf(v.y); o.z = f2bf(v.z); o.w = f2bf(v.w);
    dst[idx] = o;
  }
}

// C = A(M x K) * B(N x K)^T + bias.  128x128 tile, BK=64, 4 waves (2x2 of 64x64),
// 32x32x16 MFMA (wave tile = 2x2 subtiles of 32x32; acc 2x2 f32x16).
// A/B frag: lane holds row (l&31), k-slice (l>>5)*8..+7 of each K=16 step.
// C/D: col = lane&31, row = (reg&3) + 8*(reg>>2) + 4*(lane>>5)  [m74/m101].
// EPI=0: QKV scatter epilogue (bf16).  EPI=1: fp32 row-major C.
// Epilogues stage C through the dead 32KB LDS buffer -> coalesced 16B stores.
template<int EPI>
__global__ __launch_bounds__(256) void gemm_bt(
    const unsigned short* __restrict__ A, const unsigned short* __restrict__ Bw,
    const float* __restrict__ bias, int K, int N,
    unsigned short* __restrict__ q_out, unsigned short* __restrict__ k_out,
    unsigned short* __restrict__ vt_out, float* __restrict__ c_out)
{
  __shared__ __align__(16) char lds[32768];
  char* lsA = lds;            // [128 rows][64 bf16], XOR-swizzled within row
  char* lsB = lds + 16384;
  const int tid = threadIdx.x;
  const int l = tid & 63, w = tid >> 6;
  const int wr = w >> 1, wc = w & 1;
  const int bm = blockIdx.x * 128, bn = blockIdx.y * 128;
  const int l31 = l & 31, hi = l >> 5;

  f32x16 acc[2][2] = {};

  for (int k0 = 0; k0 < K; k0 += 64) {
    #pragma unroll
    for (int c = 0; c < 4; ++c) {
      const int o = c * 4096 + tid * 16;
      const int r = o >> 7;
      const int cb = (o & 127) ^ ((r & 7) << 4);
      gload_lds16((const char*)A + ((size_t)(bm + r) * K + k0) * 2 + cb,
                  lsA + c * 4096 + (w << 10));
      gload_lds16((const char*)Bw + ((size_t)(bn + r) * K + k0) * 2 + cb,
                  lsB + c * 4096 + (w << 10));
    }
    __syncthreads();

    #pragma unroll
    for (int ks = 0; ks < 4; ++ks) {
      bf16x8 af[2], bfr[2];
      const int co = ks * 32 + hi * 16;
      #pragma unroll
      for (int s = 0; s < 2; ++s) {
        const int ra = wr * 64 + s * 32 + l31;
        af[s]  = *(const bf16x8*)(lsA + ra * 128 + (co ^ ((ra & 7) << 4)));
        const int rb = wc * 64 + s * 32 + l31;
        bfr[s] = *(const bf16x8*)(lsB + rb * 128 + (co ^ ((rb & 7) << 4)));
      }
      acc[0][0] = mfma32(af[0], bfr[0], acc[0][0]);
      acc[0][1] = mfma32(af[0], bfr[1], acc[0][1]);
      acc[1][0] = mfma32(af[1], bfr[0], acc[1][0]);
      acc[1][1] = mfma32(af[1], bfr[1], acc[1][1]);
    }
    __syncthreads();   // also frees lds for the epilogue staging below
  }

  float bv[2];
  #pragma unroll
  for (int sj = 0; sj < 2; ++sj) bv[sj] = bias[bn + wc * 64 + sj * 32 + l31];

  if (EPI == 1) {
    // fp32 out: two 64-row passes through LDS [64][512B], then coalesced copy.
    #pragma unroll
    for (int p = 0; p < 2; ++p) {
      if (wr == p) {
        #pragma unroll
        for (int si = 0; si < 2; ++si) {
          #pragma unroll
          for (int sj = 0; sj < 2; ++sj) {
            const int col = wc * 64 + sj * 32 + l31;
            #pragma unroll
            for (int e = 0; e < 16; ++e) {
              const int rl = si * 32 + (e & 3) + 8 * (e >> 2) + 4 * hi;
              *(float*)(lds + rl * 512 + ((col * 4) ^ ((rl & 7) << 4))) =
                  acc[si][sj][e] + bv[sj];
            }
          }
        }
      }
      __syncthreads();
      #pragma unroll
      for (int it = 0; it < 8; ++it) {
        const int o = it * 4096 + tid * 16;
        const int rw = o >> 9, cb = o & 511;
        uint4 v = *(const uint4*)(lds + rw * 512 + (cb ^ ((rw & 7) << 4)));
        *(uint4*)((char*)c_out + ((size_t)(bm + p * 64 + rw) * N + bn) * 4 + cb) = v;
      }
      __syncthreads();
    }
  } else {
    // QKV scatter: each block covers exactly one (sec, head, b).
    const int secb  = bn >> 11;            // 0=Q 1=K 2=V (constant per block)
    const int headb = (bn & 2047) >> 7;
    const int s0    = bm & 2047;
    const int bh    = (bm >> 11) * NHEAD + headb;

    if (secb < 2) {
      // LDS [s 128][d 128] bf16, row-swizzled
      #pragma unroll
      for (int si = 0; si < 2; ++si) {
        #pragma unroll
        for (int sj = 0; sj < 2; ++sj) {
          const int col = wc * 64 + sj * 32 + l31;
          #pragma unroll
          for (int e = 0; e < 16; ++e) {
            const int rr = wr * 64 + si * 32 + (e & 3) + 8 * (e >> 2) + 4 * hi;
            float v = acc[si][sj][e] + bv[sj];
            if (secb == 0) v *= QSCALE_L2E;
            *(unsigned short*)(lds + rr * 256 + ((col * 2) ^ ((rr & 7) << 4))) = f2bf(v);
          }
        }
      }
      __syncthreads();
      unsigned short* qk = (secb == 0) ? q_out : k_out;
      char* gbase = (char*)(qk + ((size_t)bh * S_LEN + s0) * DHEAD);
      #pragma unroll
      for (int it = 0; it < 8; ++it) {
        const int o = it * 4096 + tid * 16;
        const int s = o >> 8, db = o & 255;
        uint4 v = *(const uint4*)(lds + s * 256 + (db ^ ((s & 7) << 4)));
        *(uint4*)(gbase + (size_t)s * 256 + db) = v;
      }
    } else {
      // Vt: LDS [d 128][s 128] bf16; regs 4g..4g+3 are 4 consecutive s -> uint2
      #pragma unroll
      for (int si = 0; si < 2; ++si) {
        #pragma unroll
        for (int sj = 0; sj < 2; ++sj) {
          const int d = wc * 64 + sj * 32 + l31;
          #pragma unroll
          for (int g = 0; g < 4; ++g) {
            const int sb = wr * 64 + si * 32 + 8 * g + 4 * hi;
            uint2 pw;
            pw.x = pkbf(acc[si][sj][4 * g] + bv[sj],     acc[si][sj][4 * g + 1] + bv[sj]);
            pw.y = pkbf(acc[si][sj][4 * g + 2] + bv[sj], acc[si][sj][4 * g + 3] + bv[sj]);
            *(uint2*)(lds + d * 256 + ((sb * 2) ^ ((d & 7) << 4))) = pw;
          }
        }
      }
      __syncthreads();
      char* gbase = (char*)vt_out + ((size_t)bh * DHEAD) * (S_LEN * 2) + (size_t)s0 * 2;
      #pragma unroll
      for (int it = 0; it < 8; ++it) {
        const int o = it * 4096 + tid * 16;
        const int d = o >> 8, sb = o & 255;
        uint4 v = *(const uint4*)(lds + d * 256 + (sb ^ ((d & 7) << 4)));
        *(uint4*)(gbase + (size_t)d * (S_LEN * 2) + sb) = v;
      }
    }
  }
}

// Causal flash attention: swapped QK^T, 32 q-rows/wave, 2-phase dbuf pipeline.
// Grid: (16 q-tiles of 128 rows, 32 bh). Block: 4 waves.
__global__ __launch_bounds__(256, 2) void attn_fwd(
    const unsigned short* __restrict__ Q, const unsigned short* __restrict__ Kk,
    const unsigned short* __restrict__ Vt, unsigned short* __restrict__ O,
    const float* __restrict__ Wout, unsigned short* __restrict__ Woutb)
{
  __shared__ char lsK[2][64 * 256];    // dbuf [64 kv][128 d] bf16, XOR-swizzled
  __shared__ char lsV[2][128 * 128];   // dbuf [128 d][64 kv] bf16, XOR-swizzled
  __shared__ char lsP[4][32 * 128];    // per-wave [32 q][64 kv] bf16, XOR-swizzled
  const int tid = threadIdx.x, l = tid & 63, w = tid >> 6;
  const int row16 = l & 15, kg = l >> 4;
  const int qb = (blockIdx.y < 16) ? (15 - (int)blockIdx.x) : (int)blockIdx.x;
  const int bh = blockIdx.y;
  const int bidx = bh >> 4, head = bh & 15;

  const char* Qh = (const char*)(Q  + (size_t)bh * S_LEN * DHEAD);
  const char* Kh = (const char*)(Kk + (size_t)bh * S_LEN * DHEAD);
  const char* Vh = (const char*)(Vt + (size_t)bh * DHEAD * S_LEN);

  const int q0w = qb * 128 + w * 32;   // this wave's first q row

  bf16x8 qf[2][4];
  #pragma unroll
  for (int qs = 0; qs < 2; ++qs)
    #pragma unroll
    for (int t = 0; t < 4; ++t)
      qf[qs][t] = *(const bf16x8*)(Qh + ((size_t)(q0w + qs * 16 + row16) * DHEAD + t * 32 + kg * 8) * 2);

  float m[2]  = {-1e30f, -1e30f};
  float ls[2] = {0.f, 0.f};
  f32x4 oacc[2][8] = {};

  const int last = 2 * qb + 1;

#define STAGE(buf, kt_) do {                                                     \
    _Pragma("unroll")                                                            \
    for (int c = 0; c < 4; ++c) {                                                \
      const int o = c * 4096 + tid * 16;                                         \
      const int rk = o >> 8, cbk = (o & 255) ^ ((rk & 7) << 4);                  \
      gload_lds16(Kh + (size_t)((kt_) * 64 + rk) * 256 + cbk,                    \
                  lsK[buf] + c * 4096 + (w << 10));                              \
      const int dv = o >> 7, cbv = (o & 127) ^ ((dv & 7) << 4);                  \
      gload_lds16(Vh + (size_t)dv * 4096 + (size_t)(kt_) * 128 + cbv,            \
                  lsV[buf] + c * 4096 + (w << 10));                              \
    } } while (0)

  STAGE(0, 0);

  // ---- Wout conversion side-work (overlaps first-tile stage latency)
  {
    const int slice = (int)blockIdx.y * 16 + (int)blockIdx.x;   // 0..511
    const float4* src = (const float4*)Wout;
    ushort4* dst = (ushort4*)Woutb;
    const int base = slice * 2048;   // 512 * 2048 float4 = Wout (4M floats)
    #pragma unroll
    for (int i = 0; i < 8; ++i) {
      float4 v = src[base + i * 256 + tid];
      ushort4 o;
      o.x = f2bf(v.x); o.y = f2bf(v.y); o.z = f2bf(v.z); o.w = f2bf(v.w);
      dst[base + i * 256 + tid] = o;
    }
  }

  __syncthreads();

  int cur = 0;
  for (int kt = 0; ; ++kt) {
    if (kt < last) STAGE(cur ^ 1, kt + 1);   // prefetch next tile

    if (kt * 64 <= q0w + 31) {
      const char* Kc = lsK[cur];
      const char* Vc = lsV[cur];
      char* Pl = lsP[w];

      // ---- S^T = K Q^T
      f32x4 sc[4][2] = {};
      #pragma unroll
      for (int j = 0; j < 4; ++j) {
        const int krow = j * 16 + row16;
        const int sw = (krow & 7) << 4;
        bf16x8 kf[4];
        #pragma unroll
        for (int t = 0; t < 4; ++t)
          kf[t] = *(const bf16x8*)(Kc + krow * 256 + ((t * 64 + kg * 16) ^ sw));
        #pragma unroll
        for (int t = 0; t < 4; ++t) {
          sc[j][0] = mfma16(kf[t], qf[0][t], sc[j][0]);
          sc[j][1] = mfma16(kf[t], qf[1][t], sc[j][1]);
        }
      }

      if (kt >= 2 * qb) {  // causal mask on diagonal tiles
        #pragma unroll
        for (int j = 0; j < 4; ++j) {
          const int kvb = kt * 64 + j * 16 + kg * 4;
          #pragma unroll
          for (int qs = 0; qs < 2; ++qs) {
            const int qq = q0w + qs * 16 + row16;
            #pragma unroll
            for (int r = 0; r < 4; ++r)
              if (kvb + r > qq) sc[j][qs][r] = -1e30f;
          }
        }
      }

      // ---- online softmax (exp2 domain), defer-max (THR=8)
      float pm[2], al[2] = {1.f, 1.f};
      #pragma unroll
      for (int qs = 0; qs < 2; ++qs) {
        float mx = fmaxf(fmaxf(hmax4(sc[0][qs]), hmax4(sc[1][qs])),
                         fmaxf(hmax4(sc[2][qs]), hmax4(sc[3][qs])));
        mx = fmaxf(mx, __shfl_xor(mx, 16, 64));
        mx = fmaxf(mx, __shfl_xor(mx, 32, 64));
        pm[qs] = mx;
      }
      const bool need = (pm[0] > m[0] + 8.f) || (pm[1] > m[1] + 8.f);
      if (__any(need)) {
        const float n0 = fmaxf(m[0], pm[0]), n1 = fmaxf(m[1], pm[1]);
        al[0] = exp2f(m[0] - n0); al[1] = exp2f(m[1] - n1);
        m[0] = n0; m[1] = n1;
        float aq[2][4];
        #pragma unroll
        for (int qs2 = 0; qs2 < 2; ++qs2)
          #pragma unroll
          for (int r = 0; r < 4; ++r)
            aq[qs2][r] = __shfl(al[qs2], kg * 4 + r, 64);
        #pragma unroll
        for (int qs2 = 0; qs2 < 2; ++qs2)
          #pragma unroll
          for (int dt = 0; dt < 8; ++dt)
            #pragma unroll
            for (int r = 0; r < 4; ++r)
              oacc[qs2][dt][r] *= aq[qs2][r];
      }

      // ---- P = exp2(S - m) -> per-wave LDS (bf16, swizzled), row-sum
      #pragma unroll
      for (int qs = 0; qs < 2; ++qs) {
        const int q = qs * 16 + row16;
        const int psw = (q & 7) << 4;
        float ps = 0.f;
        #pragma unroll
        for (int j = 0; j < 4; ++j) {
          const float p0 = exp2f(sc[j][qs][0] - m[qs]);
          const float p1 = exp2f(sc[j][qs][1] - m[qs]);
          const float p2 = exp2f(sc[j][qs][2] - m[qs]);
          const float p3 = exp2f(sc[j][qs][3] - m[qs]);
          ps += (p0 + p1) + (p2 + p3);
          uint2 pw; pw.x = pkbf(p0, p1); pw.y = pkbf(p2, p3);
          *(uint2*)(Pl + q * 128 + ((j * 32 + kg * 8) ^ psw)) = pw;
        }
        ps += __shfl_xor(ps, 16, 64);
        ps += __shfl_xor(ps, 32, 64);
        ls[qs] = ls[qs] * al[qs] + ps;
      }

      // ---- O += P V  (A = P rows q, B = Vt rows d)
      bf16x8 pa[2][2];
      #pragma unroll
      for (int qs2 = 0; qs2 < 2; ++qs2) {
        const int q = qs2 * 16 + row16;
        #pragma unroll
        for (int ks = 0; ks < 2; ++ks)
          pa[qs2][ks] = *(const bf16x8*)(Pl + q * 128 + ((ks * 64 + kg * 16) ^ ((q & 7) << 4)));
      }
      #pragma unroll
      for (int dt = 0; dt < 8; ++dt) {
        const int drow = dt * 16 + row16;
        const int vsw = (drow & 7) << 4;
        bf16x8 v0 = *(const bf16x8*)(Vc + drow * 128 + ((kg * 16) ^ vsw));
        bf16x8 v1 = *(const bf16x8*)(Vc + drow * 128 + ((64 + kg * 16) ^ vsw));
        oacc[0][dt] = mfma16(pa[0][0], v0, oacc[0][dt]);
        oacc[0][dt] = mfma16(pa[0][1], v1, oacc[0][dt]);
        oacc[1][dt] = mfma16(pa[1][0], v0, oacc[1][dt]);
        oacc[1][dt] = mfma16(pa[1][1], v1, oacc[1][dt]);
      }
    }

    __syncthreads();   // drains prefetch (vmcnt) + joins waves before buffer swap
    if (kt == last) break;
    cur ^= 1;
  }
#undef STAGE

  // ---- epilogue: normalize rows, write O[b*S + q][head*128 + d] bf16
  #pragma unroll
  for (int qs2 = 0; qs2 < 2; ++qs2) {
    #pragma unroll
    for (int r = 0; r < 4; ++r) {
      const float lr = __shfl(ls[qs2], kg * 4 + r, 64);
      const float inv = 1.0f / lr;
      const int q = q0w + qs2 * 16 + kg * 4 + r;
      const size_t orow = (size_t)(bidx * S_LEN + q) * HID + (size_t)head * DHEAD;
      #pragma unroll
      for (int dt = 0; dt < 8; ++dt)
        O[orow + dt * 16 + row16] = f2bf(oacc[qs2][dt][r] * inv);
    }
  }
}

extern "C" void kernel_launch(void* const* d_in, const int* in_sizes, int n_in,
                              void* d_out, int out_size, void* d_ws, size_t ws_size,
                              hipStream_t stream) {
  const float* x    = (const float*)d_in[0];
  const float* Wqkv = (const float*)d_in[1];
  const float* bqkv = (const float*)d_in[2];
  const float* Wout = (const float*)d_in[3];
  const float* bout = (const float*)d_in[4];
  float* out = (float*)d_out;

  if (ws_size < 100663296) return;  // insufficient scratch -> clean validation fail
  char* ws = (char*)d_ws;
  unsigned short* Qb    = (unsigned short*)(ws);
  unsigned short* Kb    = (unsigned short*)(ws + 16777216);
  unsigned short* Vtb   = (unsigned short*)(ws + 2 * 16777216);
  unsigned short* xb    = (unsigned short*)(ws + 3 * 16777216);
  unsigned short* Ob    = xb;  // alias: xb dead after QKV GEMM, Ob written after
  unsigned short* Wqkvb = (unsigned short*)(ws + 4 * 16777216);
  unsigned short* Woutb = (unsigned short*)(ws + 4 * 16777216 + 25165824);

  // x + Wqkv conversion in one launch; Wout conversion folded into attn_fwd.
  cvt_two<<<2048, 256, 0, stream>>>(x, xb, 4096 * 2048 / 4,
                                    Wqkv, Wqkvb, 6144 * 2048 / 4);

  gemm_bt<0><<<dim3(32, 48), 256, 0, stream>>>(xb, Wqkvb, bqkv, 2048, 6144,
                                               Qb, Kb, Vtb, nullptr);
  attn_fwd<<<dim3(16, 32), 256, 0, stream>>>(Qb, Kb, Vtb, Ob, Wout, Woutb);
  gemm_bt<1><<<dim3(32, 16), 256, 0, stream>>>(Ob, Woutb, bout, 2048, 2048,
                                               nullptr, nullptr, nullptr, out);
}